// Round 12
// baseline (124.544 us; speedup 1.0000x reference)
//
#include <hip/hip_runtime.h>
#include <stdint.h>

// RPN proposal generation for MI355X (gfx950) — round 12.
// vs R11 (115 us; all owned kernels < 38 us; pipeline = 5 serial
// latency-bound launches):
//  - k_merge ELIMINATED: folded into k_sel2 as a last-arriver tail
//    (device-scope atomicAdd arrival counter per batch + threadfence
//    release/acquire, Guideline-16 pattern; arrCnt re-zeroed per call via
//    hipMemsetAsync -> deterministic). Phase-1 LDS arrays are dead by the
//    merge tail; keys(40KB)+boxes(76KB) overlay the same 117KB pool.
//  - capture/mask/nms unchanged (validated, absmax 0.0 R5-R11).

#define NBATCH 16
#define KSUM 4768
#define NEGF -1e9f
#define CAP 4096
#define CAPB 4096
#define PFX 1664            // matrix prefix (13 x 128 = 32*52)
#define PW 26               // u64 words per row (1664/64)
typedef unsigned long long u64;
typedef unsigned int u32;
typedef unsigned short u16;

struct Ptrs {
  const float* cls[5];
  const float* box[5];
  const float* anc;
};

__constant__ int c_hw[5]      = {65536, 16384, 4096, 1024, 256};
__constant__ int c_lghw[5]    = {16, 14, 12, 10, 8};
__constant__ int c_K[5]       = {1000, 1000, 1000, 1000, 768};
__constant__ int c_levNOff[5] = {0, 196608, 245760, 258048, 261120};
__constant__ int c_selOff[5]  = {0, 1000, 2000, 3000, 4000};
// monokey(2.3), monokey(1.75), monokey(1.1), monokey(0.2): N(0,1) guesses,
// >=20 sigma below the true per-level top-K threshold; capture ~2200 max.
__constant__ u32 c_guess[4] = {0xC0133333u, 0xBFE00000u, 0xBF8CCCCDu, 0xBE4CCCCDu};

__device__ __forceinline__ u32 monokey(float f) {
  u32 u = __float_as_uint(f);
  return (u & 0x80000000u) ? ~u : (u | 0x80000000u);
}
__device__ __forceinline__ float inv_monokey(u32 k) {
  return __uint_as_float((k & 0x80000000u) ? (k ^ 0x80000000u) : ~k);
}
__device__ __forceinline__ u64 lanemask_lt(int lane) {
  return lane ? ((~0ULL) >> (64 - lane)) : 0ULL;
}

// Bitwise replica of XLA CPU logistic (bit-exact R1-R11, absmax 0.0).
__device__ float sigmoid_xla(float x) {
  #pragma clang fp contract(off)
  float h = 0.5f * x;
  float hc = fminf(fmaxf(h, -7.90531110763549805f), 7.90531110763549805f);
  float x2 = hc * hc;
  float p = -2.76076847742355e-16f;
  p = p * x2 + 2.00018790482477e-13f;
  p = p * x2 + -8.60467152213735e-11f;
  p = p * x2 + 5.12229709037114e-08f;
  p = p * x2 + 1.48572235717979e-05f;
  p = p * x2 + 6.37261928875436e-04f;
  p = p * x2 + 4.89352455891786e-03f;
  p = hc * p;
  float q = 1.19825839466702e-06f;
  q = q * x2 + 1.18534705686654e-04f;
  q = q * x2 + 2.26843463243900e-03f;
  q = q * x2 + 4.89352518554385e-03f;
  float t = (fabsf(h) < 0.0004f) ? h : (p / q);
  return 0.5f + 0.5f * t;
}

__device__ void decode_box(float4 anc, float dx, float dy, float dw, float dh,
                           float& x0, float& y0, float& x1, float& y1, bool& keep) {
  #pragma clang fp contract(off)
  float aw = anc.z - anc.x;
  float ah = anc.w - anc.y;
  float ax = anc.x + 0.5f * aw;
  float ay = anc.y + 0.5f * ah;
  float dwc = fminf(dw, 4.135166556742356f);
  float dhc = fminf(dh, 4.135166556742356f);
  float px = dx * aw + ax;
  float py = dy * ah + ay;
  float pw = expf(dwc) * aw;
  float ph = expf(dhc) * ah;
  x0 = px - 0.5f * pw;
  y0 = py - 0.5f * ph;
  x1 = px + 0.5f * pw;
  y1 = py + 0.5f * ph;
  x0 = fminf(fmaxf(x0, 0.0f), 1024.0f);
  y0 = fminf(fmaxf(y0, 0.0f), 1024.0f);
  x1 = fminf(fmaxf(x1, 0.0f), 1024.0f);
  y1 = fminf(fmaxf(y1, 0.0f), 1024.0f);
  keep = ((x1 - x0) >= 1.0f) && ((y1 - y0) >= 1.0f);
}

// Exact (inter/denom > 0.7f) under IEEE f32 div; early-out safe.
__device__ __forceinline__ bool iou_gt(float4 a, float aa, float4 b, float ba) {
  #pragma clang fp contract(off)
  float w = fmaxf(fminf(a.z, b.z) - fmaxf(a.x, b.x), 0.0f);
  float h = fmaxf(fminf(a.w, b.w) - fmaxf(a.y, b.y), 0.0f);
  float inter = w * h;
  float denom = aa + ba - inter + 1e-9f;
  if (inter <= 0.65f * denom) return false;
  return (inter / denom) > 0.7f;
}

// Branchless-exact pair test for k_mask: reject at <=0.65*denom, accept at
// >=0.75*denom (both rounding-safe across 0.7), exact IEEE division only in
// the (rare) band, wave-ballot guarded. Bits == iou_gt.
__device__ __forceinline__ bool pair_supp(float4 a, float aa, float4 b2, float ba) {
  #pragma clang fp contract(off)
  float w = fmaxf(fminf(a.z, b2.z) - fmaxf(a.x, b2.x), 0.0f);
  float h = fmaxf(fminf(a.w, b2.w) - fmaxf(a.y, b2.y), 0.0f);
  float inter = w * h;
  float denom = aa + ba - inter + 1e-9f;
  bool p65 = inter > 0.65f * denom;
  bool p75 = inter >= 0.75f * denom;
  bool band = p65 && !p75;
  bool supp = p75;
  if (__ballot(band) != 0ULL) {
    if (band) supp = (inter / denom) > 0.7f;
  }
  return supp;
}

// ------------- k_capture: one scan, per-block private capture ---------------
__global__ __launch_bounds__(1024) void k_capture(Ptrs p, u64* __restrict__ gCand,
                                                  u32* __restrict__ gCntBlk) {
  const int blk = (int)blockIdx.x;  // 16 batches x 12 sub-blocks
  const int b = blk / 12, sub = blk % 12;
  int l, s, S;
  if (sub < 8)       { l = 0; s = sub;     S = 8; }
  else if (sub < 10) { l = 1; s = sub - 8; S = 2; }
  else if (sub == 10){ l = 2; s = 0;       S = 1; }
  else               { l = 3; s = 0;       S = 1; }
  const int hw = c_hw[l], lghw = c_lghw[l];
  const int n4 = (3 * hw) >> 2;
  const int per = n4 / S;
  const int tid = threadIdx.x, lane = tid & 63;
  const float4* base4 = (const float4*)(p.cls[l] + (size_t)b * (size_t)(3 * hw)) + (size_t)s * per;
  const int pe0 = 4 * s * per;
  const u32 gk = c_guess[l];

  __shared__ __align__(16) u64 lc[CAPB];
  __shared__ u32 lcnt;
  if (tid == 0) lcnt = 0u;
  __syncthreads();

  for (int i = tid; i < per; i += 1024) {
    float4 v = base4[i];
    float fv[4] = {v.x, v.y, v.z, v.w};
    #pragma unroll
    for (int c = 0; c < 4; ++c) {
      u32 mk = monokey(fv[c]);
      bool cc = (mk >= gk);
      u64 cb = __ballot(cc);
      if (cb) {
        if (cc) {
          int pe = pe0 + 4 * i + c;
          int a = pe >> lghw, cell = pe & (hw - 1);
          u32 nloc = (u32)(cell * 3 + a);
          int leader = __builtin_ctzll(cb);
          u32 wcnt = (u32)__popcll(cb);
          u32 bs;
          if (lane == leader) bs = atomicAdd(&lcnt, wcnt);
          bs = __shfl(bs, leader);
          u32 u = bs + (u32)__popcll(cb & lanemask_lt(lane));
          if (u < CAPB) lc[u] = (((u64)mk) << 32) | nloc;
        }
      }
    }
  }
  __syncthreads();
  const u32 cnt = lcnt;
  const u32 wn = cnt < CAPB ? cnt : CAPB;
  u64* myCand = gCand + (size_t)blk * CAPB;
  for (u32 i = tid; i < wn; i += 1024) myCand[i] = lc[i];
  if (tid == 0) gCntBlk[blk] = cnt;
}

// Parallel suffix-scan threshold find over a 2-copy histogram (stride 2048).
__device__ __forceinline__ void find_thresh(const u32* histF, int nb, u32 K,
                                            u32 cAbove, u32* wsum, u32* wsuf,
                                            u32* shOut, int tid) {
  const int lane = tid & 63, w = tid >> 6;
  u32 h0, h1;
  if (nb == 2048) {
    int b0 = 2 * tid, b1 = b0 + 1;
    h0 = histF[b0] + histF[2048 + b0];
    h1 = histF[b1] + histF[2048 + b1];
  } else {
    h0 = histF[tid] + histF[2048 + tid];
    h1 = 0u;
  }
  u32 x = h0 + h1;
  #pragma unroll
  for (int off = 1; off < 64; off <<= 1) {
    u32 v = __shfl_down(x, off);
    if (lane + off < 64) x += v;
  }
  if (lane == 0) wsum[w] = x;
  __syncthreads();
  if (tid == 0) {
    u32 acc = 0;
    wsuf[16] = 0u;
    for (int q = 15; q >= 0; --q) { acc += wsum[q]; wsuf[q] = acc; }
  }
  __syncthreads();
  u32 SUF0 = x + wsuf[w + 1];
  if (cAbove + SUF0 >= K && cAbove + SUF0 - h0 < K) {
    shOut[0] = (nb == 2048) ? (u32)(2 * tid) : (u32)tid;
    shOut[1] = cAbove + SUF0 - h0;
  }
  if (nb == 2048) {
    u32 SUF1 = SUF0 - h0;
    if (cAbove + SUF1 >= K && cAbove + SUF1 - h1 < K) {
      shOut[0] = (u32)(2 * tid + 1);
      shOut[1] = cAbove + SUF1 - h1;
    }
  }
  __syncthreads();
}

// ------------- k_sel2: radix + sort + decode + emit + last-arriver merge ----
__global__ __launch_bounds__(1024) void k_sel2(Ptrs p, const u64* __restrict__ gCand,
                                               const u32* __restrict__ gCntBlk,
                                               u64* __restrict__ keysC,
                                               u32* __restrict__ cntOut,
                                               float4* __restrict__ boxesWs,
                                               u32* __restrict__ nOut,
                                               u32* __restrict__ arrCnt) {
  const int l = (int)(blockIdx.x % 5);
  const int b = (int)(blockIdx.x / 5);
  const int hw = c_hw[l], lghw = c_lghw[l];
  const int n = 3 * hw, K = c_K[l];
  const int tid = threadIdx.x, lane = tid & 63;

  // 117,248-B pool: phase 1 = histF(16384)|slots(8192)|cand(32768)|tieN(4096)
  //                 phase 2 = keysM(40000 @0) | boxesM(76288 @40960)
  __shared__ __align__(16) char sp[117248];
  u32* histF = (u32*)sp;
  u64* slots = (u64*)(sp + 16384);
  u64* cand  = (u64*)(sp + 24576);
  u32* tieN  = (u32*)(sp + 57344);
  u64* keysM = (u64*)sp;
  float4* boxesM = (float4*)(sp + 40960);
  __shared__ u32 sh[4];
  __shared__ u32 wsum[16], wsuf[17];
  __shared__ u32 subc[8], suboff[9], subBad;
  __shared__ u32 scnt5[5];
  __shared__ int doMerge;

  slots[tid] = 0ULL;
  u32* hc = &histF[((tid >> 6) & 1) * 2048];

  if (K >= n) {
    const float* base = p.cls[l] + (size_t)b * (size_t)n;
    if (tid < n) {
      u32 mk = monokey(base[tid]);
      int a = tid >> lghw, cell = tid & (hw - 1);
      u32 nloc = (u32)(cell * 3 + a);
      slots[tid] = (((u64)mk) << 32) | (0xFFFFFFFFu - nloc);
    }
    __syncthreads();
  } else {
    int subbase, S;
    if (l == 0)      { subbase = 0;  S = 8; }
    else if (l == 1) { subbase = 8;  S = 2; }
    else if (l == 2) { subbase = 10; S = 1; }
    else             { subbase = 11; S = 1; }
    if (tid < (u32)S) subc[tid] = gCntBlk[b * 12 + subbase + tid];
    __syncthreads();
    if (tid == 0) {
      u32 acc = 0, bad = 0;
      for (int t = 0; t < S; ++t) {
        suboff[t] = acc;
        if (subc[t] > CAPB) bad = 1u;
        acc += subc[t];
      }
      suboff[S] = acc;
      subBad = bad;
    }
    __syncthreads();
    const u32 nC = suboff[S];
    u32 threshKey;
    if (!subBad && nC >= (u32)K && nC <= CAP) {
      for (int t = 0; t < S; ++t) {
        const u64* src = gCand + (size_t)(b * 12 + subbase + t) * CAPB;
        u32 c0 = suboff[t], cN = subc[t];
        for (u32 i = tid; i < cN; i += 1024) cand[c0 + i] = src[i];
      }
      for (int i = tid; i < 4096; i += 1024) histF[i] = 0u;
      __syncthreads();
      for (int i = tid; i < (int)nC; i += 1024)
        atomicAdd(&hc[(u32)(cand[i] >> 32) >> 21], 1u);
      __syncthreads();
      find_thresh(histF, 2048, (u32)K, 0u, wsum, wsuf, sh, tid);
      const u32 b0 = sh[0];
      const u32 cA0 = sh[1];
      __syncthreads();
      for (int i = tid; i < 4096; i += 1024) histF[i] = 0u;
      __syncthreads();
      for (int i = tid; i < (int)nC; i += 1024) {
        u32 mk = (u32)(cand[i] >> 32);
        if ((mk >> 21) == b0) atomicAdd(&hc[(mk >> 10) & 0x7FFu], 1u);
      }
      __syncthreads();
      find_thresh(histF, 2048, (u32)K, cA0, wsum, wsuf, sh, tid);
      const u32 b1 = sh[0];
      const u32 cA1 = sh[1];
      const u32 prefix22 = (b0 << 11) | b1;
      __syncthreads();
      for (int i = tid; i < 4096; i += 1024) histF[i] = 0u;
      __syncthreads();
      for (int i = tid; i < (int)nC; i += 1024) {
        u32 mk = (u32)(cand[i] >> 32);
        if ((mk >> 10) == prefix22) atomicAdd(&hc[mk & 0x3FFu], 1u);
      }
      __syncthreads();
      find_thresh(histF, 1024, (u32)K, cA1, wsum, wsuf, sh, tid);
      threshKey = (prefix22 << 10) | sh[0];
      if (tid == 0) { sh[2] = 0u; sh[3] = 0u; }
      __syncthreads();
      for (int i = tid; i < (int)nC; i += 1024) {
        u64 e = cand[i];
        u32 mk = (u32)(e >> 32);
        u32 nloc = (u32)(e & 0xFFFFFFFFull);
        bool gt = (mk > threshKey);
        u64 gb = __ballot(gt);
        if (gt) {
          int leader = __builtin_ctzll(gb);
          u32 wcnt = (u32)__popcll(gb);
          u32 bs;
          if (lane == leader) bs = atomicAdd(&sh[2], wcnt);
          bs = __shfl(bs, leader);
          u32 s2 = bs + (u32)__popcll(gb & lanemask_lt(lane));
          slots[s2] = (((u64)mk) << 32) | (0xFFFFFFFFu - nloc);
        } else if (mk == threshKey) {
          u32 tt = atomicAdd(&sh[3], 1u);
          if (tt < 1024u) tieN[tt] = nloc;
        }
      }
      __syncthreads();
    } else {
      // fallback (statistically never): full 3-pass global radix + selection
      const float* base = p.cls[l] + (size_t)b * (size_t)n;
      const float4* base4 = (const float4*)base;
      const int n4 = n >> 2;
      u32 prefix = 0, cAbove = 0;
      for (int pass = 0; pass < 3; ++pass) {
        for (int i = tid; i < 4096; i += 1024) histF[i] = 0u;
        __syncthreads();
        for (int i = tid; i < n4; i += 1024) {
          float4 v = base4[i];
          float fv[4] = {v.x, v.y, v.z, v.w};
          #pragma unroll
          for (int c = 0; c < 4; ++c) {
            u32 mk = monokey(fv[c]);
            if (pass == 0) atomicAdd(&hc[mk >> 21], 1u);
            else if (pass == 1) { if ((mk >> 21) == prefix) atomicAdd(&hc[(mk >> 10) & 0x7FFu], 1u); }
            else { if ((mk >> 10) == prefix) atomicAdd(&hc[mk & 0x3FFu], 1u); }
          }
        }
        __syncthreads();
        find_thresh(histF, (pass == 2) ? 1024 : 2048, (u32)K, cAbove, wsum, wsuf, sh, tid);
        u32 t = sh[0];
        cAbove = sh[1];
        prefix = (pass == 0) ? t : ((prefix << ((pass == 2) ? 10 : 11)) | t);
        __syncthreads();
      }
      threshKey = prefix;
      if (tid == 0) { sh[2] = 0u; sh[3] = 0u; }
      __syncthreads();
      for (int i = tid; i < n4; i += 1024) {
        float4 v = base4[i];
        float fv[4] = {v.x, v.y, v.z, v.w};
        #pragma unroll
        for (int c = 0; c < 4; ++c) {
          u32 mk = monokey(fv[c]);
          if (mk >= threshKey) {
            int pe = 4 * i + c;
            int a = pe >> lghw, cell = pe & (hw - 1);
            u32 nloc = (u32)(cell * 3 + a);
            if (mk > threshKey) {
              u32 s2 = atomicAdd(&sh[2], 1u);
              slots[s2] = (((u64)mk) << 32) | (0xFFFFFFFFu - nloc);
            } else {
              u32 tt = atomicAdd(&sh[3], 1u);
              if (tt < 1024u) tieN[tt] = nloc;
            }
          }
        }
      }
      __syncthreads();
    }
    if (tid == 0) {  // tie fill (need typically 1-3)
      int cnt = (int)sh[2];
      int need = K - cnt;
      int tc = (int)sh[3];
      if (tc > 1024) tc = 1024;
      for (int s2 = 0; s2 < need; ++s2) {
        u32 best = 0xFFFFFFFFu;
        int bj = -1;
        for (int i2 = 0; i2 < tc; ++i2) {
          u32 v = tieN[i2];
          if (v < best) { best = v; bj = i2; }
        }
        if (bj < 0) break;
        tieN[bj] = 0xFFFFFFFFu;
        slots[cnt + s2] = (((u64)threshKey) << 32) | (0xFFFFFFFFu - best);
      }
    }
    __syncthreads();
  }

  // hybrid bitonic sort 1024 desc (shfl intra-wave, LDS for j>=64)
  u64 v = slots[tid];
  for (int kk = 2; kk <= 1024; kk <<= 1) {
    for (int j = kk >> 1; j > 0; j >>= 1) {
      u64 pv;
      if (j >= 64) {
        __syncthreads();
        slots[tid] = v;
        __syncthreads();
        pv = slots[tid ^ j];
      } else {
        pv = __shfl_xor(v, j);
      }
      bool takeMax = (((tid & kk) == 0) == ((tid & j) == 0));
      v = takeMax ? ((pv > v) ? pv : v) : ((pv < v) ? pv : v);
    }
  }

  // decode + sigmoid + compacted emit (rank tid == reference top_k rank)
  const float4* anc4 = (const float4*)p.anc;
  const float* bxbase = p.box[l];
  const int levN = c_levNOff[l], selO = c_selOff[l];
  bool keepf = false;
  u64 outKey = 0ULL;
  if (tid < K && v != 0ULL) {
    u32 mk = (u32)(v >> 32);
    u32 nloc = 0xFFFFFFFFu - (u32)(v & 0xFFFFFFFFull);
    float logit = inv_monokey(mk);
    int cell = (int)(nloc / 3u);
    int a = (int)(nloc - 3u * (u32)cell);
    const float* dptr = bxbase + (((size_t)(b * 12 + a * 4)) << lghw) + (size_t)cell;
    float dx = dptr[0];
    float dy = dptr[(size_t)hw];
    float dw = dptr[(size_t)2 * (size_t)hw];
    float dh = dptr[(size_t)3 * (size_t)hw];
    float4 anc = anc4[levN + (int)nloc];
    float x0, y0, x1, y1;
    bool keep;
    decode_box(anc, dx, dy, dw, dh, x0, y0, x1, y1, keep);
    int pos = selO + tid;
    boxesWs[(size_t)b * KSUM + (size_t)pos] = make_float4(x0, y0, x1, y1);
    if (keep) {
      float prob = sigmoid_xla(logit);
      keepf = true;
      outKey = (((u64)__float_as_uint(prob)) << 32) | (0xFFFFFFFFu - (u32)pos);
    }
  }
  u64 bal = __ballot(keepf);
  if (lane == 0) wsum[tid >> 6] = (u32)__popcll(bal);
  __syncthreads();
  if (tid < 16) {
    u32 xx = wsum[tid], orig = xx;
    #pragma unroll
    for (int off = 1; off < 16; off <<= 1) {
      u32 vv = __shfl_up(xx, off);
      if (tid >= off) xx += vv;
    }
    wsuf[tid] = xx - orig;
    if (tid == 15) cntOut[b * 5 + l] = xx;
  }
  __syncthreads();
  if (keepf) {
    u32 cidx = wsuf[tid >> 6] + (u32)__popcll(bal & lanemask_lt(lane));
    keysC[((size_t)(b * 5 + l)) * 1000 + cidx] = outKey;
  }

  // ---- last-arriver 5-way merge (replaces the k_merge kernel) ----
  // __syncthreads drains this block's global stores (vmcnt) before release.
  __syncthreads();
  if (tid == 0) {
    __threadfence();  // release this block's keysC/boxesWs/cntOut writes
    doMerge = (atomicAdd(&arrCnt[b], 1u) == 4u) ? 1 : 0;
  }
  __syncthreads();
  if (!doMerge) return;
  __threadfence();  // acquire: all 5 blocks' writes now visible

  if (tid < 5) scnt5[tid] = cntOut[b * 5 + tid];
  __syncthreads();
  const int Nb = (int)(scnt5[0] + scnt5[1] + scnt5[2] + scnt5[3] + scnt5[4]);
  for (int i = tid; i < 5000; i += 1024) {
    int l2 = i / 1000, ii = i - l2 * 1000;
    keysM[i] = (ii < (int)scnt5[l2]) ? keysC[((size_t)(b * 5 + l2)) * 1000 + ii] : 0ULL;
  }
  for (int i = tid; i < KSUM; i += 1024) boxesM[i] = boxesWs[(size_t)b * KSUM + i];
  __syncthreads();
  #pragma unroll
  for (int q = 0; q < 5; ++q) {
    int s3 = tid + q * 1024;
    if (s3 < 5000) {
      int l2 = s3 / 1000, ii = s3 - l2 * 1000;
      if (ii < (int)scnt5[l2]) {
        u64 e = keysM[s3];
        int rank = ii;
        #pragma unroll
        for (int l3 = 0; l3 < 5; ++l3) {
          if (l3 == l2) continue;
          int base2 = l3 * 1000;
          int lo = 0, hi = (int)scnt5[l3];
          while (lo < hi) {
            int mid = (lo + hi) >> 1;
            if (keysM[base2 + mid] > e) lo = mid + 1; else hi = mid;
          }
          rank += lo;
        }
        u32 pos = 0xFFFFFFFFu - (u32)(e & 0xFFFFFFFFull);
        keysC[(size_t)b * 5000 + rank] = e;             // merged keys
        boxesWs[(size_t)b * KSUM + rank] = boxesM[pos]; // merged boxes
      }
    }
  }
  if (tid == 0) nOut[b] = (u32)Nb;
}

// ------------- k_mask: suppression bit-matrix, 2D 128x128 tiles -------------
__global__ __launch_bounds__(1024) void k_mask(const float4* __restrict__ boxesWs,
                                               const u32* __restrict__ nOut,
                                               u64* __restrict__ mat) {
  const int blk = (int)blockIdx.x;
  const int b = blk / 169;
  const int rc = blk - b * 169;
  const int ts = rc / 13, tt = rc - ts * 13;
  const int tid = threadIdx.x;
  u64* matB = mat + (size_t)b * (PW * PFX);
  const int src0 = ts << 7, tgt0 = tt << 7;
  if (ts > tt) {
    if (tid < 256) {
      int s2 = tid & 127, wsel = tid >> 7;
      matB[(size_t)(2 * tt + wsel) * PFX + (size_t)(src0 + s2)] = 0ULL;
    }
    return;
  }
  const int N = (int)nOut[b];
  const int P1 = N < PFX ? N : PFX;
  const float4* mb = boxesWs + (size_t)b * KSUM;

  __shared__ __align__(16) float4 bxS[128];
  __shared__ __align__(16) float4 bxT[128];
  __shared__ float arS[128], arT[128];
  __shared__ u64 slab[256];

  if (tid < 128) {
    int i = src0 + tid;
    float4 v = (i < P1) ? mb[i] : make_float4(0.f, 0.f, 0.f, 0.f);
    bxS[tid] = v;
    {
      #pragma clang fp contract(off)
      arS[tid] = (v.z - v.x) * (v.w - v.y);
    }
  } else if (tid < 256) {
    int j = tgt0 + (tid - 128);
    float4 v = (j < P1) ? mb[j] : make_float4(0.f, 0.f, 0.f, 0.f);
    bxT[tid - 128] = v;
    {
      #pragma clang fp contract(off)
      arT[tid - 128] = (v.z - v.x) * (v.w - v.y);
    }
  }
  __syncthreads();

  const int s = tid >> 3;    // source 0..127
  const int slc = tid & 7;   // row-slice 0..7
  const float4 my = bxS[s];
  const float myA = arS[s];
  const bool diag = (ts == tt);
  u64 p0 = 0ULL, p1 = 0ULL;
  #pragma unroll
  for (int k = 0; k < 8; ++k) {
    int t = slc + (k << 3);
    bool sp2 = pair_supp(my, myA, bxT[t], arT[t]);
    sp2 = sp2 && (!diag || (s < t));
    p0 |= ((u64)(sp2 ? 1u : 0u)) << t;
  }
  #pragma unroll
  for (int k = 8; k < 16; ++k) {
    int t = slc + (k << 3);
    bool sp2 = pair_supp(my, myA, bxT[t], arT[t]);
    sp2 = sp2 && (!diag || (s < t));
    p1 |= ((u64)(sp2 ? 1u : 0u)) << (t - 64);
  }
  #pragma unroll
  for (int off = 1; off < 8; off <<= 1) {
    p0 |= __shfl_xor(p0, off);
    p1 |= __shfl_xor(p1, off);
  }
  if (slc == 0) { slab[s * 2] = p0; slab[s * 2 + 1] = p1; }
  __syncthreads();
  if (tid < 256) {
    int s2 = tid & 127, wsel = tid >> 7;
    matB[(size_t)(2 * tt + wsel) * PFX + (size_t)(src0 + s2)] = slab[s2 * 2 + wsel];
  }
}

// ------------- k_nms: compacted parallel fixpoint (== greedy) + emit --------
__global__ __launch_bounds__(1024) void k_nms(const u64* __restrict__ keysC,
                                              const float4* __restrict__ boxesWs,
                                              const u32* __restrict__ nOut,
                                              const u64* __restrict__ mat,
                                              float* __restrict__ out) {
  const int b = blockIdx.x;
  const int tid = threadIdx.x;
  __shared__ u64 Uw[PW], Kw[PW], remK[PW], supA[PW], newKw[PW];
  __shared__ u16 ulist[PFX];
  __shared__ u16 klist[PFX];
  __shared__ u32 ubase[PW], kbase[PW];
  __shared__ int nUS, nKS;
  __shared__ u32 wbase[PW + 1];
  __shared__ int mS;
  __shared__ __align__(16) float4 keptBox[1000];
  __shared__ float keptArea[1000];
  __shared__ __align__(16) float4 chunkBox[128];
  __shared__ float chunkArea[128];
  __shared__ float chunkProb[128];
  __shared__ u32 chunkAlive[128];
  __shared__ u64 suppBy[256];
  __shared__ u64 sAB[2];

  const int N = (int)nOut[b];
  const int P1 = N < PFX ? N : PFX;
  const u64* mk = keysC + (size_t)b * 5000;
  const float4* mb = boxesWs + (size_t)b * KSUM;
  const u64* matC = mat + (size_t)b * (PW * PFX);

  if (tid < PW) {
    int lo = tid << 6;
    int nn = P1 - lo;
    Uw[tid] = (nn >= 64) ? ~0ULL : (nn > 0 ? ((1ULL << nn) - 1ULL) : 0ULL);
    Kw[tid] = 0ULL;
    remK[tid] = 0ULL;
  }
  __syncthreads();

  const int w = tid >> 5;        // 0..31 (only w<PW active in reductions)
  const int sub = tid & 31;      // 32 threads per word
  const u64* col = (w < PW) ? (matC + (size_t)w * PFX) : matC;

  for (int round = 0; round < PFX; ++round) {
    // compact U -> ulist
    if (tid == 0) {
      u32 acc = 0;
      for (int w2 = 0; w2 < PW; ++w2) { ubase[w2] = acc; acc += (u32)__popcll(Uw[w2]); }
      nUS = (int)acc;
    }
    __syncthreads();
    const int nU = nUS;
    if (nU == 0) break;
    for (int idx = tid; idx < P1; idx += 1024) {
      u64 uw = Uw[idx >> 6];
      int bit = idx & 63;
      if ((uw >> bit) & 1ULL) {
        int pos = (int)ubase[idx >> 6] + __popcll(uw & ((1ULL << bit) - 1ULL));
        ulist[pos] = (u16)idx;
      }
    }
    __syncthreads();
    // supA[w] = (OR_{j in U} col_w[j]) | remK[w]   [remK == OR over kept rows]
    {
      u64 acc = 0ULL;
      if (w < PW) {
        for (int li = sub; li < nU; li += 32) acc |= col[(int)ulist[li]];
        #pragma unroll
        for (int off = 16; off; off >>= 1) acc |= __shfl_xor(acc, off);
        if (sub == 0) supA[w] = acc | remK[w];
      }
    }
    __syncthreads();
    if (tid < PW) newKw[tid] = Uw[tid] & ~supA[tid];
    __syncthreads();
    // compact newK -> klist
    if (tid == 0) {
      u32 acc = 0;
      for (int w2 = 0; w2 < PW; ++w2) { kbase[w2] = acc; acc += (u32)__popcll(newKw[w2]); }
      nKS = (int)acc;
    }
    __syncthreads();
    const int nK = nKS;
    for (int idx = tid; idx < P1; idx += 1024) {
      u64 kw2 = newKw[idx >> 6];
      int bit = idx & 63;
      if ((kw2 >> bit) & 1ULL) {
        int pos = (int)kbase[idx >> 6] + __popcll(kw2 & ((1ULL << bit) - 1ULL));
        klist[pos] = (u16)idx;
      }
    }
    __syncthreads();
    // remK[w] |= OR_{j in newK} col_w[j]
    {
      u64 acc = 0ULL;
      if (w < PW) {
        for (int li = sub; li < nK; li += 32) acc |= col[(int)klist[li]];
        #pragma unroll
        for (int off = 16; off; off >>= 1) acc |= __shfl_xor(acc, off);
        if (sub == 0) remK[w] |= acc;
      }
    }
    __syncthreads();
    if (tid < PW) {
      u64 u = Uw[tid], nk = newKw[tid];
      u64 nr = (u & ~nk) & remK[tid];
      Uw[tid] = u & ~nk & ~nr;
      Kw[tid] |= nk;
    }
    __syncthreads();
  }

  if (tid == 0) {
    u32 acc = 0;
    for (int w2 = 0; w2 < PW; ++w2) {
      wbase[w2] = acc;
      acc += (u32)__popcll(Kw[w2]);
    }
    wbase[PW] = acc;
    mS = (acc < 1000u) ? (int)acc : 1000;
  }
  __syncthreads();
  int m = mS;

  // emit first min(kept,1000) in rank order + gather kept list for fallback
  for (int idx = tid; idx < P1; idx += 1024) {
    u64 kw = Kw[idx >> 6];
    int bit = idx & 63;
    if ((kw >> bit) & 1ULL) {
      int g = (int)wbase[idx >> 6] + __popcll(kw & ((1ULL << bit) - 1ULL));
      if (g < 1000) {
        float4 bxv = mb[idx];
        float pr = __uint_as_float((u32)(mk[idx] >> 32));
        float arv;
        {
          #pragma clang fp contract(off)
          arv = (bxv.z - bxv.x) * (bxv.w - bxv.y);
        }
        keptBox[g] = bxv;
        keptArea[g] = arv;
        ((float4*)out)[b * 1000 + g] = bxv;
        out[64000 + b * 1000 + g] = pr;
      }
    }
  }
  __syncthreads();

  // fallback: chunked greedy past the matrix prefix (rare)
  for (int cs = PFX; cs < N && m < 1000; cs += 128) {
    if (tid < 128) {
      int idx = cs + tid;
      float4 bxv = make_float4(0.f, 0.f, 0.f, 0.f);
      float arv = 0.f, pr = 0.f;
      u32 alive = 0u;
      if (idx < N) {
        bxv = mb[idx];
        pr = __uint_as_float((u32)(mk[idx] >> 32));
        {
          #pragma clang fp contract(off)
          arv = (bxv.z - bxv.x) * (bxv.w - bxv.y);
        }
        alive = 1u;
      }
      chunkBox[tid] = bxv;
      chunkArea[tid] = arv;
      chunkProb[tid] = pr;
      chunkAlive[tid] = alive;
    }
    if (tid >= 128 && tid < 384) suppBy[tid - 128] = 0ULL;
    __syncthreads();

    {  // A: chunk vs kept (8 slices/box, linear, area precheck)
      int i0 = tid & 127, sl = tid >> 7;
      float4 my = chunkBox[i0];
      float myA = chunkArea[i0];
      bool supp = false;
      #pragma unroll 4
      for (int i = sl; i < m; i += 8) {
        float ka = keptArea[i];
        float4 kb = keptBox[i];
        if (fminf(ka, myA) > 0.699f * fmaxf(ka, myA))
          supp = supp | iou_gt(kb, ka, my, myA);
      }
      if (supp) chunkAlive[i0] = 0u;
    }
    // B: intra-chunk masks with area precheck
    for (int pI = tid; pI < 16384; pI += 1024) {
      int i = pI >> 7, j = pI & 127;
      if (j < i) {
        float aj = chunkArea[j], ai = chunkArea[i];
        if (fminf(aj, ai) > 0.699f * fmaxf(aj, ai)) {
          if (iou_gt(chunkBox[j], aj, chunkBox[i], ai))
            atomicOr(&suppBy[i * 2 + (j >> 6)], 1ULL << (j & 63));
        }
      }
    }
    __syncthreads();

    // C: wave-ballot greedy resolution, sparse suppressor bits
    if (tid < 64) {
      bool aliveLo = chunkAlive[tid] != 0u;
      bool aliveHi = chunkAlive[64 + tid] != 0u;
      u64 sLL = suppBy[tid * 2];
      u64 sHL = suppBy[(64 + tid) * 2];
      u64 sHH = suppBy[(64 + tid) * 2 + 1];
      u64 uLo = sLL;
      #pragma unroll
      for (int off = 1; off < 64; off <<= 1) uLo |= __shfl_xor(uLo, off);
      u64 rem = uLo;
      while (rem) {
        int k = __builtin_ctzll(rem);
        rem &= rem - 1ULL;
        u64 A = __ballot(aliveLo);
        if (((A >> k) & 1ULL) && ((sLL >> k) & 1ULL)) aliveLo = false;
      }
      u64 A0 = __ballot(aliveLo);
      if (sHL & A0) aliveHi = false;
      u64 uHi = sHH;
      #pragma unroll
      for (int off = 1; off < 64; off <<= 1) uHi |= __shfl_xor(uHi, off);
      rem = uHi;
      while (rem) {
        int k = __builtin_ctzll(rem);
        rem &= rem - 1ULL;
        u64 A = __ballot(aliveHi);
        if (((A >> k) & 1ULL) && ((sHH >> k) & 1ULL)) aliveHi = false;
      }
      u64 A1 = __ballot(aliveHi);
      if (tid == 0) { sAB[0] = A0; sAB[1] = A1; }
    }
    __syncthreads();

    // D: emit kept in order; append to kept list
    u64 A0 = sAB[0], A1 = sAB[1];
    int total = __popcll(A0) + __popcll(A1);
    if (tid < 128) {
      bool kept = (tid < 64) ? ((A0 >> tid) & 1ULL) : ((A1 >> (tid - 64)) & 1ULL);
      if (kept) {
        int rank = (tid < 64)
                       ? __popcll(A0 & ((1ULL << tid) - 1ULL))
                       : (__popcll(A0) + __popcll(A1 & ((1ULL << (tid - 64)) - 1ULL)));
        int g = m + rank;
        if (g < 1000) {
          float4 cb = chunkBox[tid];
          keptBox[g] = cb;
          keptArea[g] = chunkArea[tid];
          ((float4*)out)[b * 1000 + g] = cb;
          out[64000 + b * 1000 + g] = chunkProb[tid];
        }
      }
    }
    m += total;
    if (m > 1000) m = 1000;
    __syncthreads();
  }

  for (int g = m + tid; g < 1000; g += 1024) {
    ((float4*)out)[b * 1000 + g] = make_float4(0.f, 0.f, 0.f, 0.f);
    out[64000 + b * 1000 + g] = NEGF;
  }
}

extern "C" void kernel_launch(void* const* d_in, const int* in_sizes, int n_in,
                              void* d_out, int out_size, void* d_ws, size_t ws_size,
                              hipStream_t stream) {
  bool interleaved = (in_sizes[1] == 16 * 12 * 256 * 256);
  Ptrs p;
  for (int l = 0; l < 5; ++l) {
    p.cls[l] = (const float*)d_in[interleaved ? (2 * l) : l];
    p.box[l] = (const float*)d_in[interleaved ? (2 * l + 1) : (5 + l)];
  }
  p.anc = (const float*)d_in[10];

  // ws layout (total 8,153,600 B == proven-safe R4-R11 footprint):
  //   keysC   @0        : 16*5000*8 = 640,000   (per-level segs, then merged)
  //   cntW    @640,000  : 80 u32 | nOut @+320 (16 u32) | arrCnt @+384 (16 u32)
  //   boxesWs @640,512  : 16*4768*16 = 1,220,608 (pos-order, then merged)
  //   gCntBlk @1,861,120: 192 u32                              [1,024 B pad]
  //   gCand   @1,862,144: 192*4096*8 = 6,291,456
  //   mat     @1,862,144: 16*26*1664*8 = 5,537,792 col-major (overlays gCand)
  u64* keysC = (u64*)d_ws;
  u32* cntW = (u32*)((char*)d_ws + 640000);
  u32* nOut = cntW + 80;
  u32* arrCnt = cntW + 96;
  float4* boxesWs = (float4*)((char*)d_ws + 640512);
  u32* gCntBlk = (u32*)((char*)d_ws + 1861120);
  u64* gCand = (u64*)((char*)d_ws + 1862144);
  u64* mat = gCand;

  hipMemsetAsync(arrCnt, 0, 64, stream);
  k_capture<<<dim3(NBATCH * 12), dim3(1024), 0, stream>>>(p, gCand, gCntBlk);
  k_sel2<<<dim3(NBATCH * 5), dim3(1024), 0, stream>>>(p, gCand, gCntBlk, keysC, cntW,
                                                      boxesWs, nOut, arrCnt);
  k_mask<<<dim3(NBATCH * 169), dim3(1024), 0, stream>>>(boxesWs, nOut, mat);
  k_nms<<<dim3(NBATCH), dim3(1024), 0, stream>>>(keysC, boxesWs, nOut, mat, (float*)d_out);
}

// Round 13
// 115.045 us; speedup vs baseline: 1.0826x; 1.0826x over previous
//
#include <hip/hip_runtime.h>
#include <stdint.h>

// RPN proposal generation for MI355X (gfx950) — round 13.
// vs R12 (124.5 us REGRESSION: last-arriver merge fold serialized the merge
// behind k_sel2's slowest block with cold locality):
//  - REVERT to R11 structure (115.2 us best): separate k_merge kernel.
//  - k_sel2 micro-trim: pass-0 histogram fused into the cand staging loop
//    (bitwise-identical histogram, one less LDS sweep + barrier).
//  - capture/mask/nms(compacted fixpoint) unchanged (validated R9-R11).

#define NBATCH 16
#define KSUM 4768
#define NEGF -1e9f
#define CAP 4096
#define CAPB 4096
#define PFX 1664            // matrix prefix (13 x 128 = 32*52)
#define PW 26               // u64 words per row (1664/64)
typedef unsigned long long u64;
typedef unsigned int u32;
typedef unsigned short u16;

struct Ptrs {
  const float* cls[5];
  const float* box[5];
  const float* anc;
};

__constant__ int c_hw[5]      = {65536, 16384, 4096, 1024, 256};
__constant__ int c_lghw[5]    = {16, 14, 12, 10, 8};
__constant__ int c_K[5]       = {1000, 1000, 1000, 1000, 768};
__constant__ int c_levNOff[5] = {0, 196608, 245760, 258048, 261120};
__constant__ int c_selOff[5]  = {0, 1000, 2000, 3000, 4000};
// monokey(2.3), monokey(1.75), monokey(1.1), monokey(0.2): N(0,1) guesses,
// >=20 sigma below the true per-level top-K threshold; capture ~2200 max.
__constant__ u32 c_guess[4] = {0xC0133333u, 0xBFE00000u, 0xBF8CCCCDu, 0xBE4CCCCDu};

__device__ __forceinline__ u32 monokey(float f) {
  u32 u = __float_as_uint(f);
  return (u & 0x80000000u) ? ~u : (u | 0x80000000u);
}
__device__ __forceinline__ float inv_monokey(u32 k) {
  return __uint_as_float((k & 0x80000000u) ? (k ^ 0x80000000u) : ~k);
}
__device__ __forceinline__ u64 lanemask_lt(int lane) {
  return lane ? ((~0ULL) >> (64 - lane)) : 0ULL;
}

// Bitwise replica of XLA CPU logistic (bit-exact R1-R12, absmax 0.0).
__device__ float sigmoid_xla(float x) {
  #pragma clang fp contract(off)
  float h = 0.5f * x;
  float hc = fminf(fmaxf(h, -7.90531110763549805f), 7.90531110763549805f);
  float x2 = hc * hc;
  float p = -2.76076847742355e-16f;
  p = p * x2 + 2.00018790482477e-13f;
  p = p * x2 + -8.60467152213735e-11f;
  p = p * x2 + 5.12229709037114e-08f;
  p = p * x2 + 1.48572235717979e-05f;
  p = p * x2 + 6.37261928875436e-04f;
  p = p * x2 + 4.89352455891786e-03f;
  p = hc * p;
  float q = 1.19825839466702e-06f;
  q = q * x2 + 1.18534705686654e-04f;
  q = q * x2 + 2.26843463243900e-03f;
  q = q * x2 + 4.89352518554385e-03f;
  float t = (fabsf(h) < 0.0004f) ? h : (p / q);
  return 0.5f + 0.5f * t;
}

__device__ void decode_box(float4 anc, float dx, float dy, float dw, float dh,
                           float& x0, float& y0, float& x1, float& y1, bool& keep) {
  #pragma clang fp contract(off)
  float aw = anc.z - anc.x;
  float ah = anc.w - anc.y;
  float ax = anc.x + 0.5f * aw;
  float ay = anc.y + 0.5f * ah;
  float dwc = fminf(dw, 4.135166556742356f);
  float dhc = fminf(dh, 4.135166556742356f);
  float px = dx * aw + ax;
  float py = dy * ah + ay;
  float pw = expf(dwc) * aw;
  float ph = expf(dhc) * ah;
  x0 = px - 0.5f * pw;
  y0 = py - 0.5f * ph;
  x1 = px + 0.5f * pw;
  y1 = py + 0.5f * ph;
  x0 = fminf(fmaxf(x0, 0.0f), 1024.0f);
  y0 = fminf(fmaxf(y0, 0.0f), 1024.0f);
  x1 = fminf(fmaxf(x1, 0.0f), 1024.0f);
  y1 = fminf(fmaxf(y1, 0.0f), 1024.0f);
  keep = ((x1 - x0) >= 1.0f) && ((y1 - y0) >= 1.0f);
}

// Exact (inter/denom > 0.7f) under IEEE f32 div; early-out safe.
__device__ __forceinline__ bool iou_gt(float4 a, float aa, float4 b, float ba) {
  #pragma clang fp contract(off)
  float w = fmaxf(fminf(a.z, b.z) - fmaxf(a.x, b.x), 0.0f);
  float h = fmaxf(fminf(a.w, b.w) - fmaxf(a.y, b.y), 0.0f);
  float inter = w * h;
  float denom = aa + ba - inter + 1e-9f;
  if (inter <= 0.65f * denom) return false;
  return (inter / denom) > 0.7f;
}

// Branchless-exact pair test for k_mask: reject at <=0.65*denom, accept at
// >=0.75*denom (both rounding-safe across 0.7), exact IEEE division only in
// the (rare) band, wave-ballot guarded. Bits == iou_gt.
__device__ __forceinline__ bool pair_supp(float4 a, float aa, float4 b2, float ba) {
  #pragma clang fp contract(off)
  float w = fmaxf(fminf(a.z, b2.z) - fmaxf(a.x, b2.x), 0.0f);
  float h = fmaxf(fminf(a.w, b2.w) - fmaxf(a.y, b2.y), 0.0f);
  float inter = w * h;
  float denom = aa + ba - inter + 1e-9f;
  bool p65 = inter > 0.65f * denom;
  bool p75 = inter >= 0.75f * denom;
  bool band = p65 && !p75;
  bool supp = p75;
  if (__ballot(band) != 0ULL) {
    if (band) supp = (inter / denom) > 0.7f;
  }
  return supp;
}

// ------------- k_capture: one scan, per-block private capture ---------------
__global__ __launch_bounds__(1024) void k_capture(Ptrs p, u64* __restrict__ gCand,
                                                  u32* __restrict__ gCntBlk) {
  const int blk = (int)blockIdx.x;  // 16 batches x 12 sub-blocks
  const int b = blk / 12, sub = blk % 12;
  int l, s, S;
  if (sub < 8)       { l = 0; s = sub;     S = 8; }
  else if (sub < 10) { l = 1; s = sub - 8; S = 2; }
  else if (sub == 10){ l = 2; s = 0;       S = 1; }
  else               { l = 3; s = 0;       S = 1; }
  const int hw = c_hw[l], lghw = c_lghw[l];
  const int n4 = (3 * hw) >> 2;
  const int per = n4 / S;
  const int tid = threadIdx.x, lane = tid & 63;
  const float4* base4 = (const float4*)(p.cls[l] + (size_t)b * (size_t)(3 * hw)) + (size_t)s * per;
  const int pe0 = 4 * s * per;
  const u32 gk = c_guess[l];

  __shared__ __align__(16) u64 lc[CAPB];
  __shared__ u32 lcnt;
  if (tid == 0) lcnt = 0u;
  __syncthreads();

  for (int i = tid; i < per; i += 1024) {
    float4 v = base4[i];
    float fv[4] = {v.x, v.y, v.z, v.w};
    #pragma unroll
    for (int c = 0; c < 4; ++c) {
      u32 mk = monokey(fv[c]);
      bool cc = (mk >= gk);
      u64 cb = __ballot(cc);
      if (cb) {
        if (cc) {
          int pe = pe0 + 4 * i + c;
          int a = pe >> lghw, cell = pe & (hw - 1);
          u32 nloc = (u32)(cell * 3 + a);
          int leader = __builtin_ctzll(cb);
          u32 wcnt = (u32)__popcll(cb);
          u32 bs;
          if (lane == leader) bs = atomicAdd(&lcnt, wcnt);
          bs = __shfl(bs, leader);
          u32 u = bs + (u32)__popcll(cb & lanemask_lt(lane));
          if (u < CAPB) lc[u] = (((u64)mk) << 32) | nloc;
        }
      }
    }
  }
  __syncthreads();
  const u32 cnt = lcnt;
  const u32 wn = cnt < CAPB ? cnt : CAPB;
  u64* myCand = gCand + (size_t)blk * CAPB;
  for (u32 i = tid; i < wn; i += 1024) myCand[i] = lc[i];
  if (tid == 0) gCntBlk[blk] = cnt;
}

// Parallel suffix-scan threshold find over a 2-copy histogram (stride 2048).
__device__ __forceinline__ void find_thresh(const u32* histF, int nb, u32 K,
                                            u32 cAbove, u32* wsum, u32* wsuf,
                                            u32* shOut, int tid) {
  const int lane = tid & 63, w = tid >> 6;
  u32 h0, h1;
  if (nb == 2048) {
    int b0 = 2 * tid, b1 = b0 + 1;
    h0 = histF[b0] + histF[2048 + b0];
    h1 = histF[b1] + histF[2048 + b1];
  } else {
    h0 = histF[tid] + histF[2048 + tid];
    h1 = 0u;
  }
  u32 x = h0 + h1;
  #pragma unroll
  for (int off = 1; off < 64; off <<= 1) {
    u32 v = __shfl_down(x, off);
    if (lane + off < 64) x += v;
  }
  if (lane == 0) wsum[w] = x;
  __syncthreads();
  if (tid == 0) {
    u32 acc = 0;
    wsuf[16] = 0u;
    for (int q = 15; q >= 0; --q) { acc += wsum[q]; wsuf[q] = acc; }
  }
  __syncthreads();
  u32 SUF0 = x + wsuf[w + 1];
  if (cAbove + SUF0 >= K && cAbove + SUF0 - h0 < K) {
    shOut[0] = (nb == 2048) ? (u32)(2 * tid) : (u32)tid;
    shOut[1] = cAbove + SUF0 - h0;
  }
  if (nb == 2048) {
    u32 SUF1 = SUF0 - h0;
    if (cAbove + SUF1 >= K && cAbove + SUF1 - h1 < K) {
      shOut[0] = (u32)(2 * tid + 1);
      shOut[1] = cAbove + SUF1 - h1;
    }
  }
  __syncthreads();
}

// ------------- k_sel2: radix over candidates + sort + decode + emit ---------
__global__ __launch_bounds__(1024) void k_sel2(Ptrs p, const u64* __restrict__ gCand,
                                               const u32* __restrict__ gCntBlk,
                                               u64* __restrict__ keysC,
                                               u32* __restrict__ cntOut,
                                               float4* __restrict__ boxesWs) {
  const int l = (int)(blockIdx.x % 5);
  const int b = (int)(blockIdx.x / 5);
  const int hw = c_hw[l], lghw = c_lghw[l];
  const int n = 3 * hw, K = c_K[l];
  const int tid = threadIdx.x, lane = tid & 63;

  __shared__ u32 histF[4096];
  __shared__ __align__(16) u64 slots[1024];
  __shared__ __align__(16) u64 cand[CAP];
  __shared__ u32 tieN[1024];
  __shared__ u32 sh[4];
  __shared__ u32 wsum[16], wsuf[17];
  __shared__ u32 subc[8], suboff[9], subBad;

  slots[tid] = 0ULL;
  u32* hc = &histF[((tid >> 6) & 1) * 2048];

  if (K >= n) {
    const float* base = p.cls[l] + (size_t)b * (size_t)n;
    if (tid < n) {
      u32 mk = monokey(base[tid]);
      int a = tid >> lghw, cell = tid & (hw - 1);
      u32 nloc = (u32)(cell * 3 + a);
      slots[tid] = (((u64)mk) << 32) | (0xFFFFFFFFu - nloc);
    }
    __syncthreads();
  } else {
    int subbase, S;
    if (l == 0)      { subbase = 0;  S = 8; }
    else if (l == 1) { subbase = 8;  S = 2; }
    else if (l == 2) { subbase = 10; S = 1; }
    else             { subbase = 11; S = 1; }
    if (tid < (u32)S) subc[tid] = gCntBlk[b * 12 + subbase + tid];
    __syncthreads();
    if (tid == 0) {
      u32 acc = 0, bad = 0;
      for (int t = 0; t < S; ++t) {
        suboff[t] = acc;
        if (subc[t] > CAPB) bad = 1u;
        acc += subc[t];
      }
      suboff[S] = acc;
      subBad = bad;
    }
    __syncthreads();
    const u32 nC = suboff[S];
    u32 threshKey;
    if (!subBad && nC >= (u32)K && nC <= CAP) {
      // fused: stage cand into LDS AND build pass-0 histogram from registers
      for (int i = tid; i < 4096; i += 1024) histF[i] = 0u;
      __syncthreads();
      for (int t = 0; t < S; ++t) {
        const u64* src = gCand + (size_t)(b * 12 + subbase + t) * CAPB;
        u32 c0 = suboff[t], cN = subc[t];
        for (u32 i = tid; i < cN; i += 1024) {
          u64 e = src[i];
          cand[c0 + i] = e;
          atomicAdd(&hc[(u32)(e >> 32) >> 21], 1u);
        }
      }
      __syncthreads();
      find_thresh(histF, 2048, (u32)K, 0u, wsum, wsuf, sh, tid);
      const u32 b0 = sh[0];
      const u32 cA0 = sh[1];
      __syncthreads();
      for (int i = tid; i < 4096; i += 1024) histF[i] = 0u;
      __syncthreads();
      for (int i = tid; i < (int)nC; i += 1024) {
        u32 mk = (u32)(cand[i] >> 32);
        if ((mk >> 21) == b0) atomicAdd(&hc[(mk >> 10) & 0x7FFu], 1u);
      }
      __syncthreads();
      find_thresh(histF, 2048, (u32)K, cA0, wsum, wsuf, sh, tid);
      const u32 b1 = sh[0];
      const u32 cA1 = sh[1];
      const u32 prefix22 = (b0 << 11) | b1;
      __syncthreads();
      for (int i = tid; i < 4096; i += 1024) histF[i] = 0u;
      __syncthreads();
      for (int i = tid; i < (int)nC; i += 1024) {
        u32 mk = (u32)(cand[i] >> 32);
        if ((mk >> 10) == prefix22) atomicAdd(&hc[mk & 0x3FFu], 1u);
      }
      __syncthreads();
      find_thresh(histF, 1024, (u32)K, cA1, wsum, wsuf, sh, tid);
      threshKey = (prefix22 << 10) | sh[0];
      if (tid == 0) { sh[2] = 0u; sh[3] = 0u; }
      __syncthreads();
      for (int i = tid; i < (int)nC; i += 1024) {
        u64 e = cand[i];
        u32 mk = (u32)(e >> 32);
        u32 nloc = (u32)(e & 0xFFFFFFFFull);
        bool gt = (mk > threshKey);
        u64 gb = __ballot(gt);
        if (gt) {
          int leader = __builtin_ctzll(gb);
          u32 wcnt = (u32)__popcll(gb);
          u32 bs;
          if (lane == leader) bs = atomicAdd(&sh[2], wcnt);
          bs = __shfl(bs, leader);
          u32 s2 = bs + (u32)__popcll(gb & lanemask_lt(lane));
          slots[s2] = (((u64)mk) << 32) | (0xFFFFFFFFu - nloc);
        } else if (mk == threshKey) {
          u32 tt = atomicAdd(&sh[3], 1u);
          if (tt < 1024u) tieN[tt] = nloc;
        }
      }
      __syncthreads();
    } else {
      // fallback (statistically never): full 3-pass global radix + selection
      const float* base = p.cls[l] + (size_t)b * (size_t)n;
      const float4* base4 = (const float4*)base;
      const int n4 = n >> 2;
      u32 prefix = 0, cAbove = 0;
      for (int pass = 0; pass < 3; ++pass) {
        for (int i = tid; i < 4096; i += 1024) histF[i] = 0u;
        __syncthreads();
        for (int i = tid; i < n4; i += 1024) {
          float4 v = base4[i];
          float fv[4] = {v.x, v.y, v.z, v.w};
          #pragma unroll
          for (int c = 0; c < 4; ++c) {
            u32 mk = monokey(fv[c]);
            if (pass == 0) atomicAdd(&hc[mk >> 21], 1u);
            else if (pass == 1) { if ((mk >> 21) == prefix) atomicAdd(&hc[(mk >> 10) & 0x7FFu], 1u); }
            else { if ((mk >> 10) == prefix) atomicAdd(&hc[mk & 0x3FFu], 1u); }
          }
        }
        __syncthreads();
        find_thresh(histF, (pass == 2) ? 1024 : 2048, (u32)K, cAbove, wsum, wsuf, sh, tid);
        u32 t = sh[0];
        cAbove = sh[1];
        prefix = (pass == 0) ? t : ((prefix << ((pass == 2) ? 10 : 11)) | t);
        __syncthreads();
      }
      threshKey = prefix;
      if (tid == 0) { sh[2] = 0u; sh[3] = 0u; }
      __syncthreads();
      for (int i = tid; i < n4; i += 1024) {
        float4 v = base4[i];
        float fv[4] = {v.x, v.y, v.z, v.w};
        #pragma unroll
        for (int c = 0; c < 4; ++c) {
          u32 mk = monokey(fv[c]);
          if (mk >= threshKey) {
            int pe = 4 * i + c;
            int a = pe >> lghw, cell = pe & (hw - 1);
            u32 nloc = (u32)(cell * 3 + a);
            if (mk > threshKey) {
              u32 s2 = atomicAdd(&sh[2], 1u);
              slots[s2] = (((u64)mk) << 32) | (0xFFFFFFFFu - nloc);
            } else {
              u32 tt = atomicAdd(&sh[3], 1u);
              if (tt < 1024u) tieN[tt] = nloc;
            }
          }
        }
      }
      __syncthreads();
    }
    if (tid == 0) {  // tie fill (need typically 1-3)
      int cnt = (int)sh[2];
      int need = K - cnt;
      int tc = (int)sh[3];
      if (tc > 1024) tc = 1024;
      for (int s2 = 0; s2 < need; ++s2) {
        u32 best = 0xFFFFFFFFu;
        int bj = -1;
        for (int i2 = 0; i2 < tc; ++i2) {
          u32 v = tieN[i2];
          if (v < best) { best = v; bj = i2; }
        }
        if (bj < 0) break;
        tieN[bj] = 0xFFFFFFFFu;
        slots[cnt + s2] = (((u64)threshKey) << 32) | (0xFFFFFFFFu - best);
      }
    }
    __syncthreads();
  }

  // hybrid bitonic sort 1024 desc (shfl intra-wave, LDS for j>=64)
  u64 v = slots[tid];
  for (int kk = 2; kk <= 1024; kk <<= 1) {
    for (int j = kk >> 1; j > 0; j >>= 1) {
      u64 pv;
      if (j >= 64) {
        __syncthreads();
        slots[tid] = v;
        __syncthreads();
        pv = slots[tid ^ j];
      } else {
        pv = __shfl_xor(v, j);
      }
      bool takeMax = (((tid & kk) == 0) == ((tid & j) == 0));
      v = takeMax ? ((pv > v) ? pv : v) : ((pv < v) ? pv : v);
    }
  }

  // decode + sigmoid + compacted emit (rank tid == reference top_k rank)
  const float4* anc4 = (const float4*)p.anc;
  const float* bxbase = p.box[l];
  const int levN = c_levNOff[l], selO = c_selOff[l];
  bool keepf = false;
  u64 outKey = 0ULL;
  if (tid < K && v != 0ULL) {
    u32 mk = (u32)(v >> 32);
    u32 nloc = 0xFFFFFFFFu - (u32)(v & 0xFFFFFFFFull);
    float logit = inv_monokey(mk);
    int cell = (int)(nloc / 3u);
    int a = (int)(nloc - 3u * (u32)cell);
    const float* dptr = bxbase + (((size_t)(b * 12 + a * 4)) << lghw) + (size_t)cell;
    float dx = dptr[0];
    float dy = dptr[(size_t)hw];
    float dw = dptr[(size_t)2 * (size_t)hw];
    float dh = dptr[(size_t)3 * (size_t)hw];
    float4 anc = anc4[levN + (int)nloc];
    float x0, y0, x1, y1;
    bool keep;
    decode_box(anc, dx, dy, dw, dh, x0, y0, x1, y1, keep);
    int pos = selO + tid;
    boxesWs[(size_t)b * KSUM + (size_t)pos] = make_float4(x0, y0, x1, y1);
    if (keep) {
      float prob = sigmoid_xla(logit);
      keepf = true;
      outKey = (((u64)__float_as_uint(prob)) << 32) | (0xFFFFFFFFu - (u32)pos);
    }
  }
  u64 bal = __ballot(keepf);
  if (lane == 0) wsum[tid >> 6] = (u32)__popcll(bal);
  __syncthreads();
  if (tid < 16) {
    u32 xx = wsum[tid], orig = xx;
    #pragma unroll
    for (int off = 1; off < 16; off <<= 1) {
      u32 vv = __shfl_up(xx, off);
      if (tid >= off) xx += vv;
    }
    wsuf[tid] = xx - orig;
    if (tid == 15) cntOut[b * 5 + l] = xx;
  }
  __syncthreads();
  if (keepf) {
    u32 cidx = wsuf[tid >> 6] + (u32)__popcll(bal & lanemask_lt(lane));
    keysC[((size_t)(b * 5 + l)) * 1000 + cidx] = outKey;
  }
}

// ------------- k_merge: 5-way rank-merge -> merged keys+boxes (in place) ----
__global__ __launch_bounds__(1024) void k_merge(u64* __restrict__ keysC,
                                                const u32* __restrict__ cnt,
                                                float4* __restrict__ boxesWs,
                                                u32* __restrict__ nOut) {
  const int b = blockIdx.x;
  const int tid = threadIdx.x;
  __shared__ u64 keys[5000];
  __shared__ __align__(16) float4 boxes[KSUM];
  __shared__ u32 scnt[5];
  if (tid < 5) scnt[tid] = cnt[b * 5 + tid];
  __syncthreads();
  const int N = (int)(scnt[0] + scnt[1] + scnt[2] + scnt[3] + scnt[4]);
  for (int i = tid; i < 5000; i += 1024) {
    int l = i / 1000, ii = i - l * 1000;
    keys[i] = (ii < (int)scnt[l]) ? keysC[((size_t)(b * 5 + l)) * 1000 + ii] : 0ULL;
  }
  for (int i = tid; i < KSUM; i += 1024) boxes[i] = boxesWs[(size_t)b * KSUM + i];
  __syncthreads();
  #pragma unroll
  for (int q = 0; q < 5; ++q) {
    int s = tid + q * 1024;
    if (s < 5000) {
      int l = s / 1000, ii = s - l * 1000;
      if (ii < (int)scnt[l]) {
        u64 e = keys[s];
        int rank = ii;
        #pragma unroll
        for (int l2 = 0; l2 < 5; ++l2) {
          if (l2 == l) continue;
          int base2 = l2 * 1000;
          int lo = 0, hi = (int)scnt[l2];
          while (lo < hi) {
            int mid = (lo + hi) >> 1;
            if (keys[base2 + mid] > e) lo = mid + 1; else hi = mid;
          }
          rank += lo;
        }
        u32 pos = 0xFFFFFFFFu - (u32)(e & 0xFFFFFFFFull);
        keysC[(size_t)b * 5000 + rank] = e;             // merged keys
        boxesWs[(size_t)b * KSUM + rank] = boxes[pos];  // merged boxes
      }
    }
  }
  if (tid == 0) nOut[b] = (u32)N;
}

// ------------- k_mask: suppression bit-matrix, 2D 128x128 tiles -------------
__global__ __launch_bounds__(1024) void k_mask(const float4* __restrict__ boxesWs,
                                               const u32* __restrict__ nOut,
                                               u64* __restrict__ mat) {
  const int blk = (int)blockIdx.x;
  const int b = blk / 169;
  const int rc = blk - b * 169;
  const int ts = rc / 13, tt = rc - ts * 13;
  const int tid = threadIdx.x;
  u64* matB = mat + (size_t)b * (PW * PFX);
  const int src0 = ts << 7, tgt0 = tt << 7;
  if (ts > tt) {
    if (tid < 256) {
      int s2 = tid & 127, wsel = tid >> 7;
      matB[(size_t)(2 * tt + wsel) * PFX + (size_t)(src0 + s2)] = 0ULL;
    }
    return;
  }
  const int N = (int)nOut[b];
  const int P1 = N < PFX ? N : PFX;
  const float4* mb = boxesWs + (size_t)b * KSUM;

  __shared__ __align__(16) float4 bxS[128];
  __shared__ __align__(16) float4 bxT[128];
  __shared__ float arS[128], arT[128];
  __shared__ u64 slab[256];

  if (tid < 128) {
    int i = src0 + tid;
    float4 v = (i < P1) ? mb[i] : make_float4(0.f, 0.f, 0.f, 0.f);
    bxS[tid] = v;
    {
      #pragma clang fp contract(off)
      arS[tid] = (v.z - v.x) * (v.w - v.y);
    }
  } else if (tid < 256) {
    int j = tgt0 + (tid - 128);
    float4 v = (j < P1) ? mb[j] : make_float4(0.f, 0.f, 0.f, 0.f);
    bxT[tid - 128] = v;
    {
      #pragma clang fp contract(off)
      arT[tid - 128] = (v.z - v.x) * (v.w - v.y);
    }
  }
  __syncthreads();

  const int s = tid >> 3;    // source 0..127
  const int slc = tid & 7;   // row-slice 0..7
  const float4 my = bxS[s];
  const float myA = arS[s];
  const bool diag = (ts == tt);
  u64 p0 = 0ULL, p1 = 0ULL;
  #pragma unroll
  for (int k = 0; k < 8; ++k) {
    int t = slc + (k << 3);
    bool sp2 = pair_supp(my, myA, bxT[t], arT[t]);
    sp2 = sp2 && (!diag || (s < t));
    p0 |= ((u64)(sp2 ? 1u : 0u)) << t;
  }
  #pragma unroll
  for (int k = 8; k < 16; ++k) {
    int t = slc + (k << 3);
    bool sp2 = pair_supp(my, myA, bxT[t], arT[t]);
    sp2 = sp2 && (!diag || (s < t));
    p1 |= ((u64)(sp2 ? 1u : 0u)) << (t - 64);
  }
  #pragma unroll
  for (int off = 1; off < 8; off <<= 1) {
    p0 |= __shfl_xor(p0, off);
    p1 |= __shfl_xor(p1, off);
  }
  if (slc == 0) { slab[s * 2] = p0; slab[s * 2 + 1] = p1; }
  __syncthreads();
  if (tid < 256) {
    int s2 = tid & 127, wsel = tid >> 7;
    matB[(size_t)(2 * tt + wsel) * PFX + (size_t)(src0 + s2)] = slab[s2 * 2 + wsel];
  }
}

// ------------- k_nms: compacted parallel fixpoint (== greedy) + emit --------
__global__ __launch_bounds__(1024) void k_nms(const u64* __restrict__ keysC,
                                              const float4* __restrict__ boxesWs,
                                              const u32* __restrict__ nOut,
                                              const u64* __restrict__ mat,
                                              float* __restrict__ out) {
  const int b = blockIdx.x;
  const int tid = threadIdx.x;
  __shared__ u64 Uw[PW], Kw[PW], remK[PW], supA[PW], newKw[PW];
  __shared__ u16 ulist[PFX];
  __shared__ u16 klist[PFX];
  __shared__ u32 ubase[PW], kbase[PW];
  __shared__ int nUS, nKS;
  __shared__ u32 wbase[PW + 1];
  __shared__ int mS;
  __shared__ __align__(16) float4 keptBox[1000];
  __shared__ float keptArea[1000];
  __shared__ __align__(16) float4 chunkBox[128];
  __shared__ float chunkArea[128];
  __shared__ float chunkProb[128];
  __shared__ u32 chunkAlive[128];
  __shared__ u64 suppBy[256];
  __shared__ u64 sAB[2];

  const int N = (int)nOut[b];
  const int P1 = N < PFX ? N : PFX;
  const u64* mk = keysC + (size_t)b * 5000;
  const float4* mb = boxesWs + (size_t)b * KSUM;
  const u64* matC = mat + (size_t)b * (PW * PFX);

  if (tid < PW) {
    int lo = tid << 6;
    int nn = P1 - lo;
    Uw[tid] = (nn >= 64) ? ~0ULL : (nn > 0 ? ((1ULL << nn) - 1ULL) : 0ULL);
    Kw[tid] = 0ULL;
    remK[tid] = 0ULL;
  }
  __syncthreads();

  const int w = tid >> 5;        // 0..31 (only w<PW active in reductions)
  const int sub = tid & 31;      // 32 threads per word
  const u64* col = (w < PW) ? (matC + (size_t)w * PFX) : matC;

  for (int round = 0; round < PFX; ++round) {
    // compact U -> ulist
    if (tid == 0) {
      u32 acc = 0;
      for (int w2 = 0; w2 < PW; ++w2) { ubase[w2] = acc; acc += (u32)__popcll(Uw[w2]); }
      nUS = (int)acc;
    }
    __syncthreads();
    const int nU = nUS;
    if (nU == 0) break;
    for (int idx = tid; idx < P1; idx += 1024) {
      u64 uw = Uw[idx >> 6];
      int bit = idx & 63;
      if ((uw >> bit) & 1ULL) {
        int pos = (int)ubase[idx >> 6] + __popcll(uw & ((1ULL << bit) - 1ULL));
        ulist[pos] = (u16)idx;
      }
    }
    __syncthreads();
    // supA[w] = (OR_{j in U} col_w[j]) | remK[w]   [remK == OR over kept rows]
    {
      u64 acc = 0ULL;
      if (w < PW) {
        for (int li = sub; li < nU; li += 32) acc |= col[(int)ulist[li]];
        #pragma unroll
        for (int off = 16; off; off >>= 1) acc |= __shfl_xor(acc, off);
        if (sub == 0) supA[w] = acc | remK[w];
      }
    }
    __syncthreads();
    if (tid < PW) newKw[tid] = Uw[tid] & ~supA[tid];
    __syncthreads();
    // compact newK -> klist
    if (tid == 0) {
      u32 acc = 0;
      for (int w2 = 0; w2 < PW; ++w2) { kbase[w2] = acc; acc += (u32)__popcll(newKw[w2]); }
      nKS = (int)acc;
    }
    __syncthreads();
    const int nK = nKS;
    for (int idx = tid; idx < P1; idx += 1024) {
      u64 kw2 = newKw[idx >> 6];
      int bit = idx & 63;
      if ((kw2 >> bit) & 1ULL) {
        int pos = (int)kbase[idx >> 6] + __popcll(kw2 & ((1ULL << bit) - 1ULL));
        klist[pos] = (u16)idx;
      }
    }
    __syncthreads();
    // remK[w] |= OR_{j in newK} col_w[j]
    {
      u64 acc = 0ULL;
      if (w < PW) {
        for (int li = sub; li < nK; li += 32) acc |= col[(int)klist[li]];
        #pragma unroll
        for (int off = 16; off; off >>= 1) acc |= __shfl_xor(acc, off);
        if (sub == 0) remK[w] |= acc;
      }
    }
    __syncthreads();
    if (tid < PW) {
      u64 u = Uw[tid], nk = newKw[tid];
      u64 nr = (u & ~nk) & remK[tid];
      Uw[tid] = u & ~nk & ~nr;
      Kw[tid] |= nk;
    }
    __syncthreads();
  }

  if (tid == 0) {
    u32 acc = 0;
    for (int w2 = 0; w2 < PW; ++w2) {
      wbase[w2] = acc;
      acc += (u32)__popcll(Kw[w2]);
    }
    wbase[PW] = acc;
    mS = (acc < 1000u) ? (int)acc : 1000;
  }
  __syncthreads();
  int m = mS;

  // emit first min(kept,1000) in rank order + gather kept list for fallback
  for (int idx = tid; idx < P1; idx += 1024) {
    u64 kw = Kw[idx >> 6];
    int bit = idx & 63;
    if ((kw >> bit) & 1ULL) {
      int g = (int)wbase[idx >> 6] + __popcll(kw & ((1ULL << bit) - 1ULL));
      if (g < 1000) {
        float4 bxv = mb[idx];
        float pr = __uint_as_float((u32)(mk[idx] >> 32));
        float arv;
        {
          #pragma clang fp contract(off)
          arv = (bxv.z - bxv.x) * (bxv.w - bxv.y);
        }
        keptBox[g] = bxv;
        keptArea[g] = arv;
        ((float4*)out)[b * 1000 + g] = bxv;
        out[64000 + b * 1000 + g] = pr;
      }
    }
  }
  __syncthreads();

  // fallback: chunked greedy past the matrix prefix (rare)
  for (int cs = PFX; cs < N && m < 1000; cs += 128) {
    if (tid < 128) {
      int idx = cs + tid;
      float4 bxv = make_float4(0.f, 0.f, 0.f, 0.f);
      float arv = 0.f, pr = 0.f;
      u32 alive = 0u;
      if (idx < N) {
        bxv = mb[idx];
        pr = __uint_as_float((u32)(mk[idx] >> 32));
        {
          #pragma clang fp contract(off)
          arv = (bxv.z - bxv.x) * (bxv.w - bxv.y);
        }
        alive = 1u;
      }
      chunkBox[tid] = bxv;
      chunkArea[tid] = arv;
      chunkProb[tid] = pr;
      chunkAlive[tid] = alive;
    }
    if (tid >= 128 && tid < 384) suppBy[tid - 128] = 0ULL;
    __syncthreads();

    {  // A: chunk vs kept (8 slices/box, linear, area precheck)
      int i0 = tid & 127, sl = tid >> 7;
      float4 my = chunkBox[i0];
      float myA = chunkArea[i0];
      bool supp = false;
      #pragma unroll 4
      for (int i = sl; i < m; i += 8) {
        float ka = keptArea[i];
        float4 kb = keptBox[i];
        if (fminf(ka, myA) > 0.699f * fmaxf(ka, myA))
          supp = supp | iou_gt(kb, ka, my, myA);
      }
      if (supp) chunkAlive[i0] = 0u;
    }
    // B: intra-chunk masks with area precheck
    for (int pI = tid; pI < 16384; pI += 1024) {
      int i = pI >> 7, j = pI & 127;
      if (j < i) {
        float aj = chunkArea[j], ai = chunkArea[i];
        if (fminf(aj, ai) > 0.699f * fmaxf(aj, ai)) {
          if (iou_gt(chunkBox[j], aj, chunkBox[i], ai))
            atomicOr(&suppBy[i * 2 + (j >> 6)], 1ULL << (j & 63));
        }
      }
    }
    __syncthreads();

    // C: wave-ballot greedy resolution, sparse suppressor bits
    if (tid < 64) {
      bool aliveLo = chunkAlive[tid] != 0u;
      bool aliveHi = chunkAlive[64 + tid] != 0u;
      u64 sLL = suppBy[tid * 2];
      u64 sHL = suppBy[(64 + tid) * 2];
      u64 sHH = suppBy[(64 + tid) * 2 + 1];
      u64 uLo = sLL;
      #pragma unroll
      for (int off = 1; off < 64; off <<= 1) uLo |= __shfl_xor(uLo, off);
      u64 rem = uLo;
      while (rem) {
        int k = __builtin_ctzll(rem);
        rem &= rem - 1ULL;
        u64 A = __ballot(aliveLo);
        if (((A >> k) & 1ULL) && ((sLL >> k) & 1ULL)) aliveLo = false;
      }
      u64 A0 = __ballot(aliveLo);
      if (sHL & A0) aliveHi = false;
      u64 uHi = sHH;
      #pragma unroll
      for (int off = 1; off < 64; off <<= 1) uHi |= __shfl_xor(uHi, off);
      rem = uHi;
      while (rem) {
        int k = __builtin_ctzll(rem);
        rem &= rem - 1ULL;
        u64 A = __ballot(aliveHi);
        if (((A >> k) & 1ULL) && ((sHH >> k) & 1ULL)) aliveHi = false;
      }
      u64 A1 = __ballot(aliveHi);
      if (tid == 0) { sAB[0] = A0; sAB[1] = A1; }
    }
    __syncthreads();

    // D: emit kept in order; append to kept list
    u64 A0 = sAB[0], A1 = sAB[1];
    int total = __popcll(A0) + __popcll(A1);
    if (tid < 128) {
      bool kept = (tid < 64) ? ((A0 >> tid) & 1ULL) : ((A1 >> (tid - 64)) & 1ULL);
      if (kept) {
        int rank = (tid < 64)
                       ? __popcll(A0 & ((1ULL << tid) - 1ULL))
                       : (__popcll(A0) + __popcll(A1 & ((1ULL << (tid - 64)) - 1ULL)));
        int g = m + rank;
        if (g < 1000) {
          float4 cb = chunkBox[tid];
          keptBox[g] = cb;
          keptArea[g] = chunkArea[tid];
          ((float4*)out)[b * 1000 + g] = cb;
          out[64000 + b * 1000 + g] = chunkProb[tid];
        }
      }
    }
    m += total;
    if (m > 1000) m = 1000;
    __syncthreads();
  }

  for (int g = m + tid; g < 1000; g += 1024) {
    ((float4*)out)[b * 1000 + g] = make_float4(0.f, 0.f, 0.f, 0.f);
    out[64000 + b * 1000 + g] = NEGF;
  }
}

extern "C" void kernel_launch(void* const* d_in, const int* in_sizes, int n_in,
                              void* d_out, int out_size, void* d_ws, size_t ws_size,
                              hipStream_t stream) {
  bool interleaved = (in_sizes[1] == 16 * 12 * 256 * 256);
  Ptrs p;
  for (int l = 0; l < 5; ++l) {
    p.cls[l] = (const float*)d_in[interleaved ? (2 * l) : l];
    p.box[l] = (const float*)d_in[interleaved ? (2 * l + 1) : (5 + l)];
  }
  p.anc = (const float*)d_in[10];

  // ws layout (total 8,153,600 B == proven-safe R4-R12 footprint):
  //   keysC   @0        : 16*5000*8 = 640,000   (per-level segs, then merged)
  //   cntW    @640,000  : 80 u32; nOut = cntW+80 (16 u32)      [512 B region]
  //   boxesWs @640,512  : 16*4768*16 = 1,220,608 (pos-order, then merged)
  //   gCntBlk @1,861,120: 192 u32                              [1,024 B pad]
  //   gCand   @1,862,144: 192*4096*8 = 6,291,456
  //   mat     @1,862,144: 16*26*1664*8 = 5,537,792 col-major (overlays gCand)
  u64* keysC = (u64*)d_ws;
  u32* cntW = (u32*)((char*)d_ws + 640000);
  u32* nOut = cntW + 80;
  float4* boxesWs = (float4*)((char*)d_ws + 640512);
  u32* gCntBlk = (u32*)((char*)d_ws + 1861120);
  u64* gCand = (u64*)((char*)d_ws + 1862144);
  u64* mat = gCand;

  k_capture<<<dim3(NBATCH * 12), dim3(1024), 0, stream>>>(p, gCand, gCntBlk);
  k_sel2<<<dim3(NBATCH * 5), dim3(1024), 0, stream>>>(p, gCand, gCntBlk, keysC, cntW, boxesWs);
  k_merge<<<dim3(NBATCH), dim3(1024), 0, stream>>>(keysC, cntW, boxesWs, nOut);
  k_mask<<<dim3(NBATCH * 169), dim3(1024), 0, stream>>>(boxesWs, nOut, mat);
  k_nms<<<dim3(NBATCH), dim3(1024), 0, stream>>>(keysC, boxesWs, nOut, mat, (float*)d_out);
}

// Round 14
// 114.025 us; speedup vs baseline: 1.0922x; 1.0089x over previous
//
#include <hip/hip_runtime.h>
#include <stdint.h>

// RPN proposal generation for MI355X (gfx950) — round 14.
// vs R13 (115.0 us, best): k_merge made KEYS-ONLY — merged key embeds pos in
// its low word, so boxes never move; k_mask/k_nms gather
// boxesWs[b*KSUM+pos] (pos-order from k_sel2) through the merged key.
// Removes k_merge's 76KB box staging + 1.2MB scattered writes. Bit-exact.
// capture/sel2/mask-core/nms-core unchanged (validated R9-R13, absmax 0.0).

#define NBATCH 16
#define KSUM 4768
#define NEGF -1e9f
#define CAP 4096
#define CAPB 4096
#define PFX 1664            // matrix prefix (13 x 128 = 32*52)
#define PW 26               // u64 words per row (1664/64)
typedef unsigned long long u64;
typedef unsigned int u32;
typedef unsigned short u16;

struct Ptrs {
  const float* cls[5];
  const float* box[5];
  const float* anc;
};

__constant__ int c_hw[5]      = {65536, 16384, 4096, 1024, 256};
__constant__ int c_lghw[5]    = {16, 14, 12, 10, 8};
__constant__ int c_K[5]       = {1000, 1000, 1000, 1000, 768};
__constant__ int c_levNOff[5] = {0, 196608, 245760, 258048, 261120};
__constant__ int c_selOff[5]  = {0, 1000, 2000, 3000, 4000};
// monokey(2.3), monokey(1.75), monokey(1.1), monokey(0.2): N(0,1) guesses,
// >=20 sigma below the true per-level top-K threshold; capture ~2200 max.
__constant__ u32 c_guess[4] = {0xC0133333u, 0xBFE00000u, 0xBF8CCCCDu, 0xBE4CCCCDu};

__device__ __forceinline__ u32 monokey(float f) {
  u32 u = __float_as_uint(f);
  return (u & 0x80000000u) ? ~u : (u | 0x80000000u);
}
__device__ __forceinline__ float inv_monokey(u32 k) {
  return __uint_as_float((k & 0x80000000u) ? (k ^ 0x80000000u) : ~k);
}
__device__ __forceinline__ u64 lanemask_lt(int lane) {
  return lane ? ((~0ULL) >> (64 - lane)) : 0ULL;
}

// Bitwise replica of XLA CPU logistic (bit-exact R1-R13, absmax 0.0).
__device__ float sigmoid_xla(float x) {
  #pragma clang fp contract(off)
  float h = 0.5f * x;
  float hc = fminf(fmaxf(h, -7.90531110763549805f), 7.90531110763549805f);
  float x2 = hc * hc;
  float p = -2.76076847742355e-16f;
  p = p * x2 + 2.00018790482477e-13f;
  p = p * x2 + -8.60467152213735e-11f;
  p = p * x2 + 5.12229709037114e-08f;
  p = p * x2 + 1.48572235717979e-05f;
  p = p * x2 + 6.37261928875436e-04f;
  p = p * x2 + 4.89352455891786e-03f;
  p = hc * p;
  float q = 1.19825839466702e-06f;
  q = q * x2 + 1.18534705686654e-04f;
  q = q * x2 + 2.26843463243900e-03f;
  q = q * x2 + 4.89352518554385e-03f;
  float t = (fabsf(h) < 0.0004f) ? h : (p / q);
  return 0.5f + 0.5f * t;
}

__device__ void decode_box(float4 anc, float dx, float dy, float dw, float dh,
                           float& x0, float& y0, float& x1, float& y1, bool& keep) {
  #pragma clang fp contract(off)
  float aw = anc.z - anc.x;
  float ah = anc.w - anc.y;
  float ax = anc.x + 0.5f * aw;
  float ay = anc.y + 0.5f * ah;
  float dwc = fminf(dw, 4.135166556742356f);
  float dhc = fminf(dh, 4.135166556742356f);
  float px = dx * aw + ax;
  float py = dy * ah + ay;
  float pw = expf(dwc) * aw;
  float ph = expf(dhc) * ah;
  x0 = px - 0.5f * pw;
  y0 = py - 0.5f * ph;
  x1 = px + 0.5f * pw;
  y1 = py + 0.5f * ph;
  x0 = fminf(fmaxf(x0, 0.0f), 1024.0f);
  y0 = fminf(fmaxf(y0, 0.0f), 1024.0f);
  x1 = fminf(fmaxf(x1, 0.0f), 1024.0f);
  y1 = fminf(fmaxf(y1, 0.0f), 1024.0f);
  keep = ((x1 - x0) >= 1.0f) && ((y1 - y0) >= 1.0f);
}

// Exact (inter/denom > 0.7f) under IEEE f32 div; early-out safe.
__device__ __forceinline__ bool iou_gt(float4 a, float aa, float4 b, float ba) {
  #pragma clang fp contract(off)
  float w = fmaxf(fminf(a.z, b.z) - fmaxf(a.x, b.x), 0.0f);
  float h = fmaxf(fminf(a.w, b.w) - fmaxf(a.y, b.y), 0.0f);
  float inter = w * h;
  float denom = aa + ba - inter + 1e-9f;
  if (inter <= 0.65f * denom) return false;
  return (inter / denom) > 0.7f;
}

// Branchless-exact pair test for k_mask: reject at <=0.65*denom, accept at
// >=0.75*denom (both rounding-safe across 0.7), exact IEEE division only in
// the (rare) band, wave-ballot guarded. Bits == iou_gt.
__device__ __forceinline__ bool pair_supp(float4 a, float aa, float4 b2, float ba) {
  #pragma clang fp contract(off)
  float w = fmaxf(fminf(a.z, b2.z) - fmaxf(a.x, b2.x), 0.0f);
  float h = fmaxf(fminf(a.w, b2.w) - fmaxf(a.y, b2.y), 0.0f);
  float inter = w * h;
  float denom = aa + ba - inter + 1e-9f;
  bool p65 = inter > 0.65f * denom;
  bool p75 = inter >= 0.75f * denom;
  bool band = p65 && !p75;
  bool supp = p75;
  if (__ballot(band) != 0ULL) {
    if (band) supp = (inter / denom) > 0.7f;
  }
  return supp;
}

// ------------- k_capture: one scan, per-block private capture ---------------
__global__ __launch_bounds__(1024) void k_capture(Ptrs p, u64* __restrict__ gCand,
                                                  u32* __restrict__ gCntBlk) {
  const int blk = (int)blockIdx.x;  // 16 batches x 12 sub-blocks
  const int b = blk / 12, sub = blk % 12;
  int l, s, S;
  if (sub < 8)       { l = 0; s = sub;     S = 8; }
  else if (sub < 10) { l = 1; s = sub - 8; S = 2; }
  else if (sub == 10){ l = 2; s = 0;       S = 1; }
  else               { l = 3; s = 0;       S = 1; }
  const int hw = c_hw[l], lghw = c_lghw[l];
  const int n4 = (3 * hw) >> 2;
  const int per = n4 / S;
  const int tid = threadIdx.x, lane = tid & 63;
  const float4* base4 = (const float4*)(p.cls[l] + (size_t)b * (size_t)(3 * hw)) + (size_t)s * per;
  const int pe0 = 4 * s * per;
  const u32 gk = c_guess[l];

  __shared__ __align__(16) u64 lc[CAPB];
  __shared__ u32 lcnt;
  if (tid == 0) lcnt = 0u;
  __syncthreads();

  for (int i = tid; i < per; i += 1024) {
    float4 v = base4[i];
    float fv[4] = {v.x, v.y, v.z, v.w};
    #pragma unroll
    for (int c = 0; c < 4; ++c) {
      u32 mk = monokey(fv[c]);
      bool cc = (mk >= gk);
      u64 cb = __ballot(cc);
      if (cb) {
        if (cc) {
          int pe = pe0 + 4 * i + c;
          int a = pe >> lghw, cell = pe & (hw - 1);
          u32 nloc = (u32)(cell * 3 + a);
          int leader = __builtin_ctzll(cb);
          u32 wcnt = (u32)__popcll(cb);
          u32 bs;
          if (lane == leader) bs = atomicAdd(&lcnt, wcnt);
          bs = __shfl(bs, leader);
          u32 u = bs + (u32)__popcll(cb & lanemask_lt(lane));
          if (u < CAPB) lc[u] = (((u64)mk) << 32) | nloc;
        }
      }
    }
  }
  __syncthreads();
  const u32 cnt = lcnt;
  const u32 wn = cnt < CAPB ? cnt : CAPB;
  u64* myCand = gCand + (size_t)blk * CAPB;
  for (u32 i = tid; i < wn; i += 1024) myCand[i] = lc[i];
  if (tid == 0) gCntBlk[blk] = cnt;
}

// Parallel suffix-scan threshold find over a 2-copy histogram (stride 2048).
__device__ __forceinline__ void find_thresh(const u32* histF, int nb, u32 K,
                                            u32 cAbove, u32* wsum, u32* wsuf,
                                            u32* shOut, int tid) {
  const int lane = tid & 63, w = tid >> 6;
  u32 h0, h1;
  if (nb == 2048) {
    int b0 = 2 * tid, b1 = b0 + 1;
    h0 = histF[b0] + histF[2048 + b0];
    h1 = histF[b1] + histF[2048 + b1];
  } else {
    h0 = histF[tid] + histF[2048 + tid];
    h1 = 0u;
  }
  u32 x = h0 + h1;
  #pragma unroll
  for (int off = 1; off < 64; off <<= 1) {
    u32 v = __shfl_down(x, off);
    if (lane + off < 64) x += v;
  }
  if (lane == 0) wsum[w] = x;
  __syncthreads();
  if (tid == 0) {
    u32 acc = 0;
    wsuf[16] = 0u;
    for (int q = 15; q >= 0; --q) { acc += wsum[q]; wsuf[q] = acc; }
  }
  __syncthreads();
  u32 SUF0 = x + wsuf[w + 1];
  if (cAbove + SUF0 >= K && cAbove + SUF0 - h0 < K) {
    shOut[0] = (nb == 2048) ? (u32)(2 * tid) : (u32)tid;
    shOut[1] = cAbove + SUF0 - h0;
  }
  if (nb == 2048) {
    u32 SUF1 = SUF0 - h0;
    if (cAbove + SUF1 >= K && cAbove + SUF1 - h1 < K) {
      shOut[0] = (u32)(2 * tid + 1);
      shOut[1] = cAbove + SUF1 - h1;
    }
  }
  __syncthreads();
}

// ------------- k_sel2: radix over candidates + sort + decode + emit ---------
__global__ __launch_bounds__(1024) void k_sel2(Ptrs p, const u64* __restrict__ gCand,
                                               const u32* __restrict__ gCntBlk,
                                               u64* __restrict__ keysC,
                                               u32* __restrict__ cntOut,
                                               float4* __restrict__ boxesWs) {
  const int l = (int)(blockIdx.x % 5);
  const int b = (int)(blockIdx.x / 5);
  const int hw = c_hw[l], lghw = c_lghw[l];
  const int n = 3 * hw, K = c_K[l];
  const int tid = threadIdx.x, lane = tid & 63;

  __shared__ u32 histF[4096];
  __shared__ __align__(16) u64 slots[1024];
  __shared__ __align__(16) u64 cand[CAP];
  __shared__ u32 tieN[1024];
  __shared__ u32 sh[4];
  __shared__ u32 wsum[16], wsuf[17];
  __shared__ u32 subc[8], suboff[9], subBad;

  slots[tid] = 0ULL;
  u32* hc = &histF[((tid >> 6) & 1) * 2048];

  if (K >= n) {
    const float* base = p.cls[l] + (size_t)b * (size_t)n;
    if (tid < n) {
      u32 mk = monokey(base[tid]);
      int a = tid >> lghw, cell = tid & (hw - 1);
      u32 nloc = (u32)(cell * 3 + a);
      slots[tid] = (((u64)mk) << 32) | (0xFFFFFFFFu - nloc);
    }
    __syncthreads();
  } else {
    int subbase, S;
    if (l == 0)      { subbase = 0;  S = 8; }
    else if (l == 1) { subbase = 8;  S = 2; }
    else if (l == 2) { subbase = 10; S = 1; }
    else             { subbase = 11; S = 1; }
    if (tid < (u32)S) subc[tid] = gCntBlk[b * 12 + subbase + tid];
    __syncthreads();
    if (tid == 0) {
      u32 acc = 0, bad = 0;
      for (int t = 0; t < S; ++t) {
        suboff[t] = acc;
        if (subc[t] > CAPB) bad = 1u;
        acc += subc[t];
      }
      suboff[S] = acc;
      subBad = bad;
    }
    __syncthreads();
    const u32 nC = suboff[S];
    u32 threshKey;
    if (!subBad && nC >= (u32)K && nC <= CAP) {
      // fused: stage cand into LDS AND build pass-0 histogram from registers
      for (int i = tid; i < 4096; i += 1024) histF[i] = 0u;
      __syncthreads();
      for (int t = 0; t < S; ++t) {
        const u64* src = gCand + (size_t)(b * 12 + subbase + t) * CAPB;
        u32 c0 = suboff[t], cN = subc[t];
        for (u32 i = tid; i < cN; i += 1024) {
          u64 e = src[i];
          cand[c0 + i] = e;
          atomicAdd(&hc[(u32)(e >> 32) >> 21], 1u);
        }
      }
      __syncthreads();
      find_thresh(histF, 2048, (u32)K, 0u, wsum, wsuf, sh, tid);
      const u32 b0 = sh[0];
      const u32 cA0 = sh[1];
      __syncthreads();
      for (int i = tid; i < 4096; i += 1024) histF[i] = 0u;
      __syncthreads();
      for (int i = tid; i < (int)nC; i += 1024) {
        u32 mk = (u32)(cand[i] >> 32);
        if ((mk >> 21) == b0) atomicAdd(&hc[(mk >> 10) & 0x7FFu], 1u);
      }
      __syncthreads();
      find_thresh(histF, 2048, (u32)K, cA0, wsum, wsuf, sh, tid);
      const u32 b1 = sh[0];
      const u32 cA1 = sh[1];
      const u32 prefix22 = (b0 << 11) | b1;
      __syncthreads();
      for (int i = tid; i < 4096; i += 1024) histF[i] = 0u;
      __syncthreads();
      for (int i = tid; i < (int)nC; i += 1024) {
        u32 mk = (u32)(cand[i] >> 32);
        if ((mk >> 10) == prefix22) atomicAdd(&hc[mk & 0x3FFu], 1u);
      }
      __syncthreads();
      find_thresh(histF, 1024, (u32)K, cA1, wsum, wsuf, sh, tid);
      threshKey = (prefix22 << 10) | sh[0];
      if (tid == 0) { sh[2] = 0u; sh[3] = 0u; }
      __syncthreads();
      for (int i = tid; i < (int)nC; i += 1024) {
        u64 e = cand[i];
        u32 mk = (u32)(e >> 32);
        u32 nloc = (u32)(e & 0xFFFFFFFFull);
        bool gt = (mk > threshKey);
        u64 gb = __ballot(gt);
        if (gt) {
          int leader = __builtin_ctzll(gb);
          u32 wcnt = (u32)__popcll(gb);
          u32 bs;
          if (lane == leader) bs = atomicAdd(&sh[2], wcnt);
          bs = __shfl(bs, leader);
          u32 s2 = bs + (u32)__popcll(gb & lanemask_lt(lane));
          slots[s2] = (((u64)mk) << 32) | (0xFFFFFFFFu - nloc);
        } else if (mk == threshKey) {
          u32 tt = atomicAdd(&sh[3], 1u);
          if (tt < 1024u) tieN[tt] = nloc;
        }
      }
      __syncthreads();
    } else {
      // fallback (statistically never): full 3-pass global radix + selection
      const float* base = p.cls[l] + (size_t)b * (size_t)n;
      const float4* base4 = (const float4*)base;
      const int n4 = n >> 2;
      u32 prefix = 0, cAbove = 0;
      for (int pass = 0; pass < 3; ++pass) {
        for (int i = tid; i < 4096; i += 1024) histF[i] = 0u;
        __syncthreads();
        for (int i = tid; i < n4; i += 1024) {
          float4 v = base4[i];
          float fv[4] = {v.x, v.y, v.z, v.w};
          #pragma unroll
          for (int c = 0; c < 4; ++c) {
            u32 mk = monokey(fv[c]);
            if (pass == 0) atomicAdd(&hc[mk >> 21], 1u);
            else if (pass == 1) { if ((mk >> 21) == prefix) atomicAdd(&hc[(mk >> 10) & 0x7FFu], 1u); }
            else { if ((mk >> 10) == prefix) atomicAdd(&hc[mk & 0x3FFu], 1u); }
          }
        }
        __syncthreads();
        find_thresh(histF, (pass == 2) ? 1024 : 2048, (u32)K, cAbove, wsum, wsuf, sh, tid);
        u32 t = sh[0];
        cAbove = sh[1];
        prefix = (pass == 0) ? t : ((prefix << ((pass == 2) ? 10 : 11)) | t);
        __syncthreads();
      }
      threshKey = prefix;
      if (tid == 0) { sh[2] = 0u; sh[3] = 0u; }
      __syncthreads();
      for (int i = tid; i < n4; i += 1024) {
        float4 v = base4[i];
        float fv[4] = {v.x, v.y, v.z, v.w};
        #pragma unroll
        for (int c = 0; c < 4; ++c) {
          u32 mk = monokey(fv[c]);
          if (mk >= threshKey) {
            int pe = 4 * i + c;
            int a = pe >> lghw, cell = pe & (hw - 1);
            u32 nloc = (u32)(cell * 3 + a);
            if (mk > threshKey) {
              u32 s2 = atomicAdd(&sh[2], 1u);
              slots[s2] = (((u64)mk) << 32) | (0xFFFFFFFFu - nloc);
            } else {
              u32 tt = atomicAdd(&sh[3], 1u);
              if (tt < 1024u) tieN[tt] = nloc;
            }
          }
        }
      }
      __syncthreads();
    }
    if (tid == 0) {  // tie fill (need typically 1-3)
      int cnt = (int)sh[2];
      int need = K - cnt;
      int tc = (int)sh[3];
      if (tc > 1024) tc = 1024;
      for (int s2 = 0; s2 < need; ++s2) {
        u32 best = 0xFFFFFFFFu;
        int bj = -1;
        for (int i2 = 0; i2 < tc; ++i2) {
          u32 v = tieN[i2];
          if (v < best) { best = v; bj = i2; }
        }
        if (bj < 0) break;
        tieN[bj] = 0xFFFFFFFFu;
        slots[cnt + s2] = (((u64)threshKey) << 32) | (0xFFFFFFFFu - best);
      }
    }
    __syncthreads();
  }

  // hybrid bitonic sort 1024 desc (shfl intra-wave, LDS for j>=64)
  u64 v = slots[tid];
  for (int kk = 2; kk <= 1024; kk <<= 1) {
    for (int j = kk >> 1; j > 0; j >>= 1) {
      u64 pv;
      if (j >= 64) {
        __syncthreads();
        slots[tid] = v;
        __syncthreads();
        pv = slots[tid ^ j];
      } else {
        pv = __shfl_xor(v, j);
      }
      bool takeMax = (((tid & kk) == 0) == ((tid & j) == 0));
      v = takeMax ? ((pv > v) ? pv : v) : ((pv < v) ? pv : v);
    }
  }

  // decode + sigmoid + compacted emit (rank tid == reference top_k rank)
  const float4* anc4 = (const float4*)p.anc;
  const float* bxbase = p.box[l];
  const int levN = c_levNOff[l], selO = c_selOff[l];
  bool keepf = false;
  u64 outKey = 0ULL;
  if (tid < K && v != 0ULL) {
    u32 mk = (u32)(v >> 32);
    u32 nloc = 0xFFFFFFFFu - (u32)(v & 0xFFFFFFFFull);
    float logit = inv_monokey(mk);
    int cell = (int)(nloc / 3u);
    int a = (int)(nloc - 3u * (u32)cell);
    const float* dptr = bxbase + (((size_t)(b * 12 + a * 4)) << lghw) + (size_t)cell;
    float dx = dptr[0];
    float dy = dptr[(size_t)hw];
    float dw = dptr[(size_t)2 * (size_t)hw];
    float dh = dptr[(size_t)3 * (size_t)hw];
    float4 anc = anc4[levN + (int)nloc];
    float x0, y0, x1, y1;
    bool keep;
    decode_box(anc, dx, dy, dw, dh, x0, y0, x1, y1, keep);
    int pos = selO + tid;
    boxesWs[(size_t)b * KSUM + (size_t)pos] = make_float4(x0, y0, x1, y1);
    if (keep) {
      float prob = sigmoid_xla(logit);
      keepf = true;
      outKey = (((u64)__float_as_uint(prob)) << 32) | (0xFFFFFFFFu - (u32)pos);
    }
  }
  u64 bal = __ballot(keepf);
  if (lane == 0) wsum[tid >> 6] = (u32)__popcll(bal);
  __syncthreads();
  if (tid < 16) {
    u32 xx = wsum[tid], orig = xx;
    #pragma unroll
    for (int off = 1; off < 16; off <<= 1) {
      u32 vv = __shfl_up(xx, off);
      if (tid >= off) xx += vv;
    }
    wsuf[tid] = xx - orig;
    if (tid == 15) cntOut[b * 5 + l] = xx;
  }
  __syncthreads();
  if (keepf) {
    u32 cidx = wsuf[tid >> 6] + (u32)__popcll(bal & lanemask_lt(lane));
    keysC[((size_t)(b * 5 + l)) * 1000 + cidx] = outKey;
  }
}

// ------------- k_merge: KEYS-ONLY 5-way rank-merge (pos rides in key) -------
__global__ __launch_bounds__(1024) void k_merge(u64* __restrict__ keysC,
                                                const u32* __restrict__ cnt,
                                                u32* __restrict__ nOut) {
  const int b = blockIdx.x;
  const int tid = threadIdx.x;
  __shared__ u64 keys[5000];
  __shared__ u32 scnt[5];
  if (tid < 5) scnt[tid] = cnt[b * 5 + tid];
  __syncthreads();
  const int N = (int)(scnt[0] + scnt[1] + scnt[2] + scnt[3] + scnt[4]);
  for (int i = tid; i < 5000; i += 1024) {
    int l = i / 1000, ii = i - l * 1000;
    keys[i] = (ii < (int)scnt[l]) ? keysC[((size_t)(b * 5 + l)) * 1000 + ii] : 0ULL;
  }
  __syncthreads();
  #pragma unroll
  for (int q = 0; q < 5; ++q) {
    int s = tid + q * 1024;
    if (s < 5000) {
      int l = s / 1000, ii = s - l * 1000;
      if (ii < (int)scnt[l]) {
        u64 e = keys[s];
        int rank = ii;
        #pragma unroll
        for (int l2 = 0; l2 < 5; ++l2) {
          if (l2 == l) continue;
          int base2 = l2 * 1000;
          int lo = 0, hi = (int)scnt[l2];
          while (lo < hi) {
            int mid = (lo + hi) >> 1;
            if (keys[base2 + mid] > e) lo = mid + 1; else hi = mid;
          }
          rank += lo;
        }
        keysC[(size_t)b * 5000 + rank] = e;  // merged keys (pos in low word)
      }
    }
  }
  if (tid == 0) nOut[b] = (u32)N;
}

// ------------- k_mask: suppression bit-matrix, 2D 128x128 tiles -------------
// Boxes gathered via merged key's embedded pos (boxesWs stays pos-order).
__global__ __launch_bounds__(1024) void k_mask(const u64* __restrict__ keysC,
                                               const float4* __restrict__ boxesWs,
                                               const u32* __restrict__ nOut,
                                               u64* __restrict__ mat) {
  const int blk = (int)blockIdx.x;
  const int b = blk / 169;
  const int rc = blk - b * 169;
  const int ts = rc / 13, tt = rc - ts * 13;
  const int tid = threadIdx.x;
  u64* matB = mat + (size_t)b * (PW * PFX);
  const int src0 = ts << 7, tgt0 = tt << 7;
  if (ts > tt) {
    if (tid < 256) {
      int s2 = tid & 127, wsel = tid >> 7;
      matB[(size_t)(2 * tt + wsel) * PFX + (size_t)(src0 + s2)] = 0ULL;
    }
    return;
  }
  const int N = (int)nOut[b];
  const int P1 = N < PFX ? N : PFX;
  const u64* mkeys = keysC + (size_t)b * 5000;
  const float4* mb = boxesWs + (size_t)b * KSUM;

  __shared__ __align__(16) float4 bxS[128];
  __shared__ __align__(16) float4 bxT[128];
  __shared__ float arS[128], arT[128];
  __shared__ u64 slab[256];

  if (tid < 128) {
    int i = src0 + tid;
    float4 v = make_float4(0.f, 0.f, 0.f, 0.f);
    if (i < P1) {
      u32 pos = 0xFFFFFFFFu - (u32)(mkeys[i] & 0xFFFFFFFFull);
      v = mb[pos];
    }
    bxS[tid] = v;
    {
      #pragma clang fp contract(off)
      arS[tid] = (v.z - v.x) * (v.w - v.y);
    }
  } else if (tid < 256) {
    int j = tgt0 + (tid - 128);
    float4 v = make_float4(0.f, 0.f, 0.f, 0.f);
    if (j < P1) {
      u32 pos = 0xFFFFFFFFu - (u32)(mkeys[j] & 0xFFFFFFFFull);
      v = mb[pos];
    }
    bxT[tid - 128] = v;
    {
      #pragma clang fp contract(off)
      arT[tid - 128] = (v.z - v.x) * (v.w - v.y);
    }
  }
  __syncthreads();

  const int s = tid >> 3;    // source 0..127
  const int slc = tid & 7;   // row-slice 0..7
  const float4 my = bxS[s];
  const float myA = arS[s];
  const bool diag = (ts == tt);
  u64 p0 = 0ULL, p1 = 0ULL;
  #pragma unroll
  for (int k = 0; k < 8; ++k) {
    int t = slc + (k << 3);
    bool sp2 = pair_supp(my, myA, bxT[t], arT[t]);
    sp2 = sp2 && (!diag || (s < t));
    p0 |= ((u64)(sp2 ? 1u : 0u)) << t;
  }
  #pragma unroll
  for (int k = 8; k < 16; ++k) {
    int t = slc + (k << 3);
    bool sp2 = pair_supp(my, myA, bxT[t], arT[t]);
    sp2 = sp2 && (!diag || (s < t));
    p1 |= ((u64)(sp2 ? 1u : 0u)) << (t - 64);
  }
  #pragma unroll
  for (int off = 1; off < 8; off <<= 1) {
    p0 |= __shfl_xor(p0, off);
    p1 |= __shfl_xor(p1, off);
  }
  if (slc == 0) { slab[s * 2] = p0; slab[s * 2 + 1] = p1; }
  __syncthreads();
  if (tid < 256) {
    int s2 = tid & 127, wsel = tid >> 7;
    matB[(size_t)(2 * tt + wsel) * PFX + (size_t)(src0 + s2)] = slab[s2 * 2 + wsel];
  }
}

// ------------- k_nms: compacted parallel fixpoint (== greedy) + emit --------
__global__ __launch_bounds__(1024) void k_nms(const u64* __restrict__ keysC,
                                              const float4* __restrict__ boxesWs,
                                              const u32* __restrict__ nOut,
                                              const u64* __restrict__ mat,
                                              float* __restrict__ out) {
  const int b = blockIdx.x;
  const int tid = threadIdx.x;
  __shared__ u64 Uw[PW], Kw[PW], remK[PW], supA[PW], newKw[PW];
  __shared__ u16 ulist[PFX];
  __shared__ u16 klist[PFX];
  __shared__ u32 ubase[PW], kbase[PW];
  __shared__ int nUS, nKS;
  __shared__ u32 wbase[PW + 1];
  __shared__ int mS;
  __shared__ __align__(16) float4 keptBox[1000];
  __shared__ float keptArea[1000];
  __shared__ __align__(16) float4 chunkBox[128];
  __shared__ float chunkArea[128];
  __shared__ float chunkProb[128];
  __shared__ u32 chunkAlive[128];
  __shared__ u64 suppBy[256];
  __shared__ u64 sAB[2];

  const int N = (int)nOut[b];
  const int P1 = N < PFX ? N : PFX;
  const u64* mk = keysC + (size_t)b * 5000;
  const float4* mb = boxesWs + (size_t)b * KSUM;  // pos-order
  const u64* matC = mat + (size_t)b * (PW * PFX);

  if (tid < PW) {
    int lo = tid << 6;
    int nn = P1 - lo;
    Uw[tid] = (nn >= 64) ? ~0ULL : (nn > 0 ? ((1ULL << nn) - 1ULL) : 0ULL);
    Kw[tid] = 0ULL;
    remK[tid] = 0ULL;
  }
  __syncthreads();

  const int w = tid >> 5;        // 0..31 (only w<PW active in reductions)
  const int sub = tid & 31;      // 32 threads per word
  const u64* col = (w < PW) ? (matC + (size_t)w * PFX) : matC;

  for (int round = 0; round < PFX; ++round) {
    // compact U -> ulist
    if (tid == 0) {
      u32 acc = 0;
      for (int w2 = 0; w2 < PW; ++w2) { ubase[w2] = acc; acc += (u32)__popcll(Uw[w2]); }
      nUS = (int)acc;
    }
    __syncthreads();
    const int nU = nUS;
    if (nU == 0) break;
    for (int idx = tid; idx < P1; idx += 1024) {
      u64 uw = Uw[idx >> 6];
      int bit = idx & 63;
      if ((uw >> bit) & 1ULL) {
        int pos = (int)ubase[idx >> 6] + __popcll(uw & ((1ULL << bit) - 1ULL));
        ulist[pos] = (u16)idx;
      }
    }
    __syncthreads();
    // supA[w] = (OR_{j in U} col_w[j]) | remK[w]   [remK == OR over kept rows]
    {
      u64 acc = 0ULL;
      if (w < PW) {
        for (int li = sub; li < nU; li += 32) acc |= col[(int)ulist[li]];
        #pragma unroll
        for (int off = 16; off; off >>= 1) acc |= __shfl_xor(acc, off);
        if (sub == 0) supA[w] = acc | remK[w];
      }
    }
    __syncthreads();
    if (tid < PW) newKw[tid] = Uw[tid] & ~supA[tid];
    __syncthreads();
    // compact newK -> klist
    if (tid == 0) {
      u32 acc = 0;
      for (int w2 = 0; w2 < PW; ++w2) { kbase[w2] = acc; acc += (u32)__popcll(newKw[w2]); }
      nKS = (int)acc;
    }
    __syncthreads();
    const int nK = nKS;
    for (int idx = tid; idx < P1; idx += 1024) {
      u64 kw2 = newKw[idx >> 6];
      int bit = idx & 63;
      if ((kw2 >> bit) & 1ULL) {
        int pos = (int)kbase[idx >> 6] + __popcll(kw2 & ((1ULL << bit) - 1ULL));
        klist[pos] = (u16)idx;
      }
    }
    __syncthreads();
    // remK[w] |= OR_{j in newK} col_w[j]
    {
      u64 acc = 0ULL;
      if (w < PW) {
        for (int li = sub; li < nK; li += 32) acc |= col[(int)klist[li]];
        #pragma unroll
        for (int off = 16; off; off >>= 1) acc |= __shfl_xor(acc, off);
        if (sub == 0) remK[w] |= acc;
      }
    }
    __syncthreads();
    if (tid < PW) {
      u64 u = Uw[tid], nk = newKw[tid];
      u64 nr = (u & ~nk) & remK[tid];
      Uw[tid] = u & ~nk & ~nr;
      Kw[tid] |= nk;
    }
    __syncthreads();
  }

  if (tid == 0) {
    u32 acc = 0;
    for (int w2 = 0; w2 < PW; ++w2) {
      wbase[w2] = acc;
      acc += (u32)__popcll(Kw[w2]);
    }
    wbase[PW] = acc;
    mS = (acc < 1000u) ? (int)acc : 1000;
  }
  __syncthreads();
  int m = mS;

  // emit first min(kept,1000) in rank order + gather kept list for fallback
  for (int idx = tid; idx < P1; idx += 1024) {
    u64 kw = Kw[idx >> 6];
    int bit = idx & 63;
    if ((kw >> bit) & 1ULL) {
      int g = (int)wbase[idx >> 6] + __popcll(kw & ((1ULL << bit) - 1ULL));
      if (g < 1000) {
        u64 e = mk[idx];
        u32 pos = 0xFFFFFFFFu - (u32)(e & 0xFFFFFFFFull);
        float4 bxv = mb[pos];
        float pr = __uint_as_float((u32)(e >> 32));
        float arv;
        {
          #pragma clang fp contract(off)
          arv = (bxv.z - bxv.x) * (bxv.w - bxv.y);
        }
        keptBox[g] = bxv;
        keptArea[g] = arv;
        ((float4*)out)[b * 1000 + g] = bxv;
        out[64000 + b * 1000 + g] = pr;
      }
    }
  }
  __syncthreads();

  // fallback: chunked greedy past the matrix prefix (rare)
  for (int cs = PFX; cs < N && m < 1000; cs += 128) {
    if (tid < 128) {
      int idx = cs + tid;
      float4 bxv = make_float4(0.f, 0.f, 0.f, 0.f);
      float arv = 0.f, pr = 0.f;
      u32 alive = 0u;
      if (idx < N) {
        u64 e = mk[idx];
        u32 pos = 0xFFFFFFFFu - (u32)(e & 0xFFFFFFFFull);
        bxv = mb[pos];
        pr = __uint_as_float((u32)(e >> 32));
        {
          #pragma clang fp contract(off)
          arv = (bxv.z - bxv.x) * (bxv.w - bxv.y);
        }
        alive = 1u;
      }
      chunkBox[tid] = bxv;
      chunkArea[tid] = arv;
      chunkProb[tid] = pr;
      chunkAlive[tid] = alive;
    }
    if (tid >= 128 && tid < 384) suppBy[tid - 128] = 0ULL;
    __syncthreads();

    {  // A: chunk vs kept (8 slices/box, linear, area precheck)
      int i0 = tid & 127, sl = tid >> 7;
      float4 my = chunkBox[i0];
      float myA = chunkArea[i0];
      bool supp = false;
      #pragma unroll 4
      for (int i = sl; i < m; i += 8) {
        float ka = keptArea[i];
        float4 kb = keptBox[i];
        if (fminf(ka, myA) > 0.699f * fmaxf(ka, myA))
          supp = supp | iou_gt(kb, ka, my, myA);
      }
      if (supp) chunkAlive[i0] = 0u;
    }
    // B: intra-chunk masks with area precheck
    for (int pI = tid; pI < 16384; pI += 1024) {
      int i = pI >> 7, j = pI & 127;
      if (j < i) {
        float aj = chunkArea[j], ai = chunkArea[i];
        if (fminf(aj, ai) > 0.699f * fmaxf(aj, ai)) {
          if (iou_gt(chunkBox[j], aj, chunkBox[i], ai))
            atomicOr(&suppBy[i * 2 + (j >> 6)], 1ULL << (j & 63));
        }
      }
    }
    __syncthreads();

    // C: wave-ballot greedy resolution, sparse suppressor bits
    if (tid < 64) {
      bool aliveLo = chunkAlive[tid] != 0u;
      bool aliveHi = chunkAlive[64 + tid] != 0u;
      u64 sLL = suppBy[tid * 2];
      u64 sHL = suppBy[(64 + tid) * 2];
      u64 sHH = suppBy[(64 + tid) * 2 + 1];
      u64 uLo = sLL;
      #pragma unroll
      for (int off = 1; off < 64; off <<= 1) uLo |= __shfl_xor(uLo, off);
      u64 rem = uLo;
      while (rem) {
        int k = __builtin_ctzll(rem);
        rem &= rem - 1ULL;
        u64 A = __ballot(aliveLo);
        if (((A >> k) & 1ULL) && ((sLL >> k) & 1ULL)) aliveLo = false;
      }
      u64 A0 = __ballot(aliveLo);
      if (sHL & A0) aliveHi = false;
      u64 uHi = sHH;
      #pragma unroll
      for (int off = 1; off < 64; off <<= 1) uHi |= __shfl_xor(uHi, off);
      rem = uHi;
      while (rem) {
        int k = __builtin_ctzll(rem);
        rem &= rem - 1ULL;
        u64 A = __ballot(aliveHi);
        if (((A >> k) & 1ULL) && ((sHH >> k) & 1ULL)) aliveHi = false;
      }
      u64 A1 = __ballot(aliveHi);
      if (tid == 0) { sAB[0] = A0; sAB[1] = A1; }
    }
    __syncthreads();

    // D: emit kept in order; append to kept list
    u64 A0 = sAB[0], A1 = sAB[1];
    int total = __popcll(A0) + __popcll(A1);
    if (tid < 128) {
      bool kept = (tid < 64) ? ((A0 >> tid) & 1ULL) : ((A1 >> (tid - 64)) & 1ULL);
      if (kept) {
        int rank = (tid < 64)
                       ? __popcll(A0 & ((1ULL << tid) - 1ULL))
                       : (__popcll(A0) + __popcll(A1 & ((1ULL << (tid - 64)) - 1ULL)));
        int g = m + rank;
        if (g < 1000) {
          float4 cb = chunkBox[tid];
          keptBox[g] = cb;
          keptArea[g] = chunkArea[tid];
          ((float4*)out)[b * 1000 + g] = cb;
          out[64000 + b * 1000 + g] = chunkProb[tid];
        }
      }
    }
    m += total;
    if (m > 1000) m = 1000;
    __syncthreads();
  }

  for (int g = m + tid; g < 1000; g += 1024) {
    ((float4*)out)[b * 1000 + g] = make_float4(0.f, 0.f, 0.f, 0.f);
    out[64000 + b * 1000 + g] = NEGF;
  }
}

extern "C" void kernel_launch(void* const* d_in, const int* in_sizes, int n_in,
                              void* d_out, int out_size, void* d_ws, size_t ws_size,
                              hipStream_t stream) {
  bool interleaved = (in_sizes[1] == 16 * 12 * 256 * 256);
  Ptrs p;
  for (int l = 0; l < 5; ++l) {
    p.cls[l] = (const float*)d_in[interleaved ? (2 * l) : l];
    p.box[l] = (const float*)d_in[interleaved ? (2 * l + 1) : (5 + l)];
  }
  p.anc = (const float*)d_in[10];

  // ws layout (total 8,153,600 B == proven-safe R4-R13 footprint):
  //   keysC   @0        : 16*5000*8 = 640,000   (per-level segs, then merged)
  //   cntW    @640,000  : 80 u32; nOut = cntW+80 (16 u32)      [512 B region]
  //   boxesWs @640,512  : 16*4768*16 = 1,220,608 (pos-order, NEVER permuted)
  //   gCntBlk @1,861,120: 192 u32                              [1,024 B pad]
  //   gCand   @1,862,144: 192*4096*8 = 6,291,456
  //   mat     @1,862,144: 16*26*1664*8 = 5,537,792 col-major (overlays gCand)
  u64* keysC = (u64*)d_ws;
  u32* cntW = (u32*)((char*)d_ws + 640000);
  u32* nOut = cntW + 80;
  float4* boxesWs = (float4*)((char*)d_ws + 640512);
  u32* gCntBlk = (u32*)((char*)d_ws + 1861120);
  u64* gCand = (u64*)((char*)d_ws + 1862144);
  u64* mat = gCand;

  k_capture<<<dim3(NBATCH * 12), dim3(1024), 0, stream>>>(p, gCand, gCntBlk);
  k_sel2<<<dim3(NBATCH * 5), dim3(1024), 0, stream>>>(p, gCand, gCntBlk, keysC, cntW, boxesWs);
  k_merge<<<dim3(NBATCH), dim3(1024), 0, stream>>>(keysC, cntW, nOut);
  k_mask<<<dim3(NBATCH * 169), dim3(1024), 0, stream>>>(keysC, boxesWs, nOut, mat);
  k_nms<<<dim3(NBATCH), dim3(1024), 0, stream>>>(keysC, boxesWs, nOut, mat, (float*)d_out);
}